// Round 5
// baseline (2004.920 us; speedup 1.0000x reference)
//
#include <hip/hip_runtime.h>
#include <float.h>

#define BB 2
#define LL 2048
#define EE 1024
#define HH 16
#define DHD 64
#define WIN 128

// ---------------- GEMM: out = A @ W^T + bias (NT, both K-contiguous) --------
// A: [M, 1024], W: [N=1024, 1024] row-major. BM=BN=128, BK=16, 256 thr, 8x8.
// Double-buffered LDS with register prefetch.
__global__ __launch_bounds__(256) void gemm_nt_f32(
    const float* __restrict__ A, const float* __restrict__ W,
    const float* __restrict__ bias, float* __restrict__ dst, int qkv_layout)
{
    __shared__ float As[2][16][132];
    __shared__ float Bs[2][16][132];
    const int tid = threadIdx.x;
    const int tx = tid & 15, ty = tid >> 4;
    const int row0 = blockIdx.y * 128, col0 = blockIdx.x * 128;
    const int lr = tid >> 2;          // 0..63 (row within half-tile)
    const int lc = (tid & 3) * 4;     // k offset 0,4,8,12

    float acc[8][8];
#pragma unroll
    for (int i = 0; i < 8; i++)
#pragma unroll
        for (int j = 0; j < 8; j++) acc[i][j] = 0.f;

    // stage tile 0
#pragma unroll
    for (int it = 0; it < 2; it++) {
        const int r = lr + it * 64;
        float4 a = *(const float4*)&A[(size_t)(row0 + r) * EE + lc];
        As[0][lc + 0][r] = a.x; As[0][lc + 1][r] = a.y;
        As[0][lc + 2][r] = a.z; As[0][lc + 3][r] = a.w;
        float4 b = *(const float4*)&W[(size_t)(col0 + r) * EE + lc];
        Bs[0][lc + 0][r] = b.x; Bs[0][lc + 1][r] = b.y;
        Bs[0][lc + 2][r] = b.z; Bs[0][lc + 3][r] = b.w;
    }
    __syncthreads();

    int cur = 0;
    for (int t = 0; t < EE / 16; t++) {
        float4 pa[2], pb[2];
        const bool more = (t + 1) < EE / 16;
        if (more) {
            const int k0 = (t + 1) * 16;
#pragma unroll
            for (int it = 0; it < 2; it++) {
                const int r = lr + it * 64;
                pa[it] = *(const float4*)&A[(size_t)(row0 + r) * EE + k0 + lc];
                pb[it] = *(const float4*)&W[(size_t)(col0 + r) * EE + k0 + lc];
            }
        }
#pragma unroll
        for (int kk = 0; kk < 16; kk++) {
            float4 a0 = *(const float4*)&As[cur][kk][ty * 8];
            float4 a1 = *(const float4*)&As[cur][kk][ty * 8 + 4];
            float4 b0 = *(const float4*)&Bs[cur][kk][tx * 8];
            float4 b1 = *(const float4*)&Bs[cur][kk][tx * 8 + 4];
            float av[8] = {a0.x, a0.y, a0.z, a0.w, a1.x, a1.y, a1.z, a1.w};
            float bv[8] = {b0.x, b0.y, b0.z, b0.w, b1.x, b1.y, b1.z, b1.w};
#pragma unroll
            for (int i = 0; i < 8; i++)
#pragma unroll
                for (int j = 0; j < 8; j++) acc[i][j] += av[i] * bv[j];
        }
        if (more) {
            const int nb = cur ^ 1;
#pragma unroll
            for (int it = 0; it < 2; it++) {
                const int r = lr + it * 64;
                As[nb][lc + 0][r] = pa[it].x; As[nb][lc + 1][r] = pa[it].y;
                As[nb][lc + 2][r] = pa[it].z; As[nb][lc + 3][r] = pa[it].w;
                Bs[nb][lc + 0][r] = pb[it].x; Bs[nb][lc + 1][r] = pb[it].y;
                Bs[nb][lc + 2][r] = pb[it].z; Bs[nb][lc + 3][r] = pb[it].w;
            }
        }
        __syncthreads();
        cur ^= 1;
    }

#pragma unroll
    for (int i = 0; i < 8; i++) {
        const int m = row0 + ty * 8 + i;
#pragma unroll
        for (int j = 0; j < 8; j++) {
            const int n = col0 + tx * 8 + j;
            const float val = acc[i][j] + bias[n];
            if (qkv_layout) {
                const int b = m >> 11, l = m & (LL - 1);
                const int h = n >> 6, d = n & 63;
                dst[((size_t)(b * HH + h) * LL + l) * DHD + d] = val;
            } else {
                dst[(size_t)m * EE + n] = val;
            }
        }
    }
}

// ---------------- Wave-per-row windowed sparse attention ----------------
// Block = 256 threads = 4 waves; handles 16 consecutive query rows of one
// (b, h). Wave w processes rows i0+4w .. i0+4w+3 fully independently:
// NO __syncthreads anywhere. Allowed columns: {0} U [i-WIN, i+WIN]
// (row 0: all 2048).
__global__ __launch_bounds__(256) void attn_wave(
    const float* __restrict__ q, const float* __restrict__ k,
    const float* __restrict__ v, const float* __restrict__ pos_bias,
    float* __restrict__ attn_out)
{
    const int h = blockIdx.y;
    const int b = blockIdx.z;
    const int i0 = blockIdx.x * 16;
    const int tid = threadIdx.x;
    const int w = tid >> 6;            // wave 0..3
    const int lane = tid & 63;
    const int g = lane >> 4;           // column slot 0..3
    const int lq = lane & 15;          // dim quad 0..15

    __shared__ float sc_w[4][280];     // per-wave windowed score buffer
    __shared__ float sc_d[2048];       // dense buffer (row 0 only)

    const size_t bh = (size_t)(b * HH + h) * LL;
    const float* kbase = k + bh * DHD;
    const float* vbase = v + bh * DHD;

    for (int r = 0; r < 4; r++) {
        const int i = i0 + w * 4 + r;
        float* scb = (i == 0) ? sc_d : sc_w[w];

        int lo, ncols, extra;
        if (i == 0) { lo = 0; extra = 0; ncols = LL; }
        else {
            lo = (i - WIN > 0) ? i - WIN : 0;
            const int hi = (i + WIN < LL - 1) ? i + WIN : LL - 1;
            extra = (lo > 0) ? 1 : 0;          // column 0 prepended
            ncols = hi - lo + 1 + extra;
        }

        const float* qrow = q + (bh + i) * DHD;
        const float4 q4 = *(const float4*)(qrow + lq * 4);
        const float* pbrow = pos_bias + (size_t)i * LL;

        // ---- scores: 4 columns per iteration, 16 lanes each ----
        for (int base = 0; base < ncols; base += 4) {
            const int pos = base + g;
            int j = 0;
            float part = 0.f;
            if (pos < ncols) {
                j = (extra && pos == 0) ? 0 : lo + pos - extra;
                const float4 kv = *(const float4*)(kbase + (size_t)j * DHD + lq * 4);
                part = q4.x * kv.x + q4.y * kv.y + q4.z * kv.z + q4.w * kv.w;
            }
            part += __shfl_xor(part, 8);
            part += __shfl_xor(part, 4);
            part += __shfl_xor(part, 2);
            part += __shfl_xor(part, 1);
            if (lq == 0 && pos < ncols) {
                const float s = part * 0.125f;  // 1/sqrt(64)
                scb[pos] = (s > 0.0f) ? s + pbrow[j] : -FLT_MAX;
            }
        }

        // ---- softmax (wave shuffle reductions, no barriers) ----
        float m = -FLT_MAX;
        for (int pos = lane; pos < ncols; pos += 64) m = fmaxf(m, scb[pos]);
#pragma unroll
        for (int d = 32; d; d >>= 1) m = fmaxf(m, __shfl_xor(m, d));

        float lsum = 0.f;
        for (int pos = lane; pos < ncols; pos += 64) {
            const float p = expf(scb[pos] - m);
            scb[pos] = p;
            lsum += p;
        }
#pragma unroll
        for (int d = 32; d; d >>= 1) lsum += __shfl_xor(lsum, d);
        const float inv = 1.0f / lsum;

        // ---- PV: lane owns dim, 4 split accumulators, skip p==0 ----
        float a0 = 0.f, a1 = 0.f, a2 = 0.f, a3 = 0.f;
        int pos = 0;
        for (; pos + 4 <= ncols; pos += 4) {
            const float p0 = scb[pos], p1 = scb[pos + 1];
            const float p2 = scb[pos + 2], p3 = scb[pos + 3];
            const int jb = lo + pos - extra;
            if (p0 != 0.f) {
                const int j0 = (extra && pos == 0) ? 0 : jb;
                a0 += p0 * vbase[(size_t)j0 * DHD + lane];
            }
            if (p1 != 0.f) a1 += p1 * vbase[(size_t)(jb + 1) * DHD + lane];
            if (p2 != 0.f) a2 += p2 * vbase[(size_t)(jb + 2) * DHD + lane];
            if (p3 != 0.f) a3 += p3 * vbase[(size_t)(jb + 3) * DHD + lane];
        }
        for (; pos < ncols; pos++) {
            const float p = scb[pos];
            if (p != 0.f) {
                const int j = (extra && pos == 0) ? 0 : lo + pos - extra;
                a0 += p * vbase[(size_t)j * DHD + lane];
            }
        }

        attn_out[((size_t)(b * LL + i)) * EE + h * DHD + lane] =
            ((a0 + a1) + (a2 + a3)) * inv;
    }
}

extern "C" void kernel_launch(void* const* d_in, const int* in_sizes, int n_in,
                              void* d_out, int out_size, void* d_ws, size_t ws_size,
                              hipStream_t stream) {
    const float* x        = (const float*)d_in[0];
    const float* pos_bias = (const float*)d_in[1];
    const float* Wq = (const float*)d_in[2];
    const float* bq = (const float*)d_in[3];
    const float* Wk = (const float*)d_in[4];
    const float* bk = (const float*)d_in[5];
    const float* Wv = (const float*)d_in[6];
    const float* bv = (const float*)d_in[7];
    const float* Wo = (const float*)d_in[8];
    const float* bo = (const float*)d_in[9];
    float* out = (float*)d_out;

    const size_t QKV = (size_t)BB * HH * LL * DHD;
    float* ws   = (float*)d_ws;
    float* q    = ws;
    float* k    = ws + QKV;
    float* v    = ws + 2 * QKV;
    float* attn = ws + 3 * QKV;                 // [B, L, E]

    dim3 blk(256);
    dim3 g1(EE / 128, (BB * LL) / 128);
    gemm_nt_f32<<<g1, blk, 0, stream>>>(x, Wq, bq, q, 1);
    gemm_nt_f32<<<g1, blk, 0, stream>>>(x, Wk, bk, k, 1);
    gemm_nt_f32<<<g1, blk, 0, stream>>>(x, Wv, bv, v, 1);

    attn_wave<<<dim3(LL / 16, HH, BB), 256, 0, stream>>>(q, k, v, pos_bias, attn);

    gemm_nt_f32<<<g1, blk, 0, stream>>>(attn, Wo, bo, out, 0);
}

// Round 6
// 1057.630 us; speedup vs baseline: 1.8957x; 1.8957x over previous
//
#include <hip/hip_runtime.h>
#include <float.h>

#define BB 2
#define LL 2048
#define EE 1024
#define HH 16
#define DHD 64
#define WIN 128

// ---------------- GEMM: out = A @ W^T + bias (NT, both K-contiguous) --------
__global__ __launch_bounds__(256) void gemm_nt_f32(
    const float* __restrict__ A, const float* __restrict__ W,
    const float* __restrict__ bias, float* __restrict__ dst, int qkv_layout)
{
    __shared__ float As[2][16][132];
    __shared__ float Bs[2][16][132];
    const int tid = threadIdx.x;
    const int tx = tid & 15, ty = tid >> 4;
    const int row0 = blockIdx.y * 128, col0 = blockIdx.x * 128;
    const int lr = tid >> 2;
    const int lc = (tid & 3) * 4;

    float acc[8][8];
#pragma unroll
    for (int i = 0; i < 8; i++)
#pragma unroll
        for (int j = 0; j < 8; j++) acc[i][j] = 0.f;

#pragma unroll
    for (int it = 0; it < 2; it++) {
        const int r = lr + it * 64;
        float4 a = *(const float4*)&A[(size_t)(row0 + r) * EE + lc];
        As[0][lc + 0][r] = a.x; As[0][lc + 1][r] = a.y;
        As[0][lc + 2][r] = a.z; As[0][lc + 3][r] = a.w;
        float4 b = *(const float4*)&W[(size_t)(col0 + r) * EE + lc];
        Bs[0][lc + 0][r] = b.x; Bs[0][lc + 1][r] = b.y;
        Bs[0][lc + 2][r] = b.z; Bs[0][lc + 3][r] = b.w;
    }
    __syncthreads();

    int cur = 0;
    for (int t = 0; t < EE / 16; t++) {
        float4 pa[2], pb[2];
        const bool more = (t + 1) < EE / 16;
        if (more) {
            const int k0 = (t + 1) * 16;
#pragma unroll
            for (int it = 0; it < 2; it++) {
                const int r = lr + it * 64;
                pa[it] = *(const float4*)&A[(size_t)(row0 + r) * EE + k0 + lc];
                pb[it] = *(const float4*)&W[(size_t)(col0 + r) * EE + k0 + lc];
            }
        }
#pragma unroll
        for (int kk = 0; kk < 16; kk++) {
            float4 a0 = *(const float4*)&As[cur][kk][ty * 8];
            float4 a1 = *(const float4*)&As[cur][kk][ty * 8 + 4];
            float4 b0 = *(const float4*)&Bs[cur][kk][tx * 8];
            float4 b1 = *(const float4*)&Bs[cur][kk][tx * 8 + 4];
            float av[8] = {a0.x, a0.y, a0.z, a0.w, a1.x, a1.y, a1.z, a1.w};
            float bv[8] = {b0.x, b0.y, b0.z, b0.w, b1.x, b1.y, b1.z, b1.w};
#pragma unroll
            for (int i = 0; i < 8; i++)
#pragma unroll
                for (int j = 0; j < 8; j++) acc[i][j] += av[i] * bv[j];
        }
        if (more) {
            const int nb = cur ^ 1;
#pragma unroll
            for (int it = 0; it < 2; it++) {
                const int r = lr + it * 64;
                As[nb][lc + 0][r] = pa[it].x; As[nb][lc + 1][r] = pa[it].y;
                As[nb][lc + 2][r] = pa[it].z; As[nb][lc + 3][r] = pa[it].w;
                Bs[nb][lc + 0][r] = pb[it].x; Bs[nb][lc + 1][r] = pb[it].y;
                Bs[nb][lc + 2][r] = pb[it].z; Bs[nb][lc + 3][r] = pb[it].w;
            }
        }
        __syncthreads();
        cur ^= 1;
    }

#pragma unroll
    for (int i = 0; i < 8; i++) {
        const int m = row0 + ty * 8 + i;
#pragma unroll
        for (int j = 0; j < 8; j++) {
            const int n = col0 + tx * 8 + j;
            const float val = acc[i][j] + bias[n];
            if (qkv_layout) {
                const int b = m >> 11, l = m & (LL - 1);
                const int h = n >> 6, d = n & 63;
                dst[((size_t)(b * HH + h) * LL + l) * DHD + d] = val;
            } else {
                dst[(size_t)m * EE + n] = val;
            }
        }
    }
}

// ---------------- Wave-per-row windowed sparse attention, XCD-local --------
// 1-D grid of 4096 blocks; bid = chunk*32 + head so all blocks of one head
// share bid%8 -> same XCD (round-robin heuristic) -> 4 heads/XCD = 4 MB K+V
// working set = L2 size. Block = 4 waves, 16 consecutive rows, no barriers.
__global__ __launch_bounds__(256) void attn_wave2(
    const float* __restrict__ q, const float* __restrict__ k,
    const float* __restrict__ v, const float* __restrict__ pos_bias,
    float* __restrict__ attn_out)
{
    const int bid = blockIdx.x;
    const int head = bid & 31;         // b*16+h
    const int chunk = bid >> 5;
    const int b = head >> 4;
    const int h = head & 15;
    const int i0 = chunk * 16;
    const int tid = threadIdx.x;
    const int w = tid >> 6;            // wave 0..3
    const int lane = tid & 63;
    const int g = lane >> 4;           // column slot 0..3
    const int lq = lane & 15;          // dim quad 0..15

    __shared__ float sc_w[4][288];     // per-wave windowed score buffer
    __shared__ float sc_d[2048];       // dense buffer (row 0 only)

    const size_t bh = (size_t)(b * HH + h) * LL;
    const float* kbase = k + bh * DHD;
    const float* vbase = v + bh * DHD;

    for (int r = 0; r < 4; r++) {
        const int i = i0 + w * 4 + r;
        float* scb = (i == 0) ? sc_d : sc_w[w];

        int lo, ncols, extra;
        if (i == 0) { lo = 0; extra = 0; ncols = LL; }
        else {
            lo = (i - WIN > 0) ? i - WIN : 0;
            const int hi = (i + WIN < LL - 1) ? i + WIN : LL - 1;
            extra = (lo > 0) ? 1 : 0;          // column 0 prepended
            ncols = hi - lo + 1 + extra;
        }

        const float4 q4 = *(const float4*)(q + (bh + i) * DHD + lq * 4);
        const float* pbrow = pos_bias + (size_t)i * LL;

        // ---- scores: 4 columns/iter, 16 lanes each; main loop unguarded ----
        int base = 0;
#pragma unroll 2
        for (; base + 4 <= ncols; base += 4) {
            const int pos = base + g;
            const int j = (extra && pos == 0) ? 0 : lo + pos - extra;
            const float4 kv = *(const float4*)(kbase + (size_t)j * DHD + lq * 4);
            float part = q4.x * kv.x + q4.y * kv.y + q4.z * kv.z + q4.w * kv.w;
            part += __shfl_xor(part, 8);
            part += __shfl_xor(part, 4);
            part += __shfl_xor(part, 2);
            part += __shfl_xor(part, 1);
            if (lq == 0) {
                const float s = part * 0.125f;          // 1/sqrt(64)
                scb[pos] = (s > 0.0f) ? s + pbrow[j] : -FLT_MAX;
            }
        }
        if (base < ncols) {                             // tail quad
            const int pos = base + g;
            const bool ok = pos < ncols;
            int j = lo;
            float part = 0.f;
            if (ok) {
                j = (extra && pos == 0) ? 0 : lo + pos - extra;
                const float4 kv = *(const float4*)(kbase + (size_t)j * DHD + lq * 4);
                part = q4.x * kv.x + q4.y * kv.y + q4.z * kv.z + q4.w * kv.w;
            }
            part += __shfl_xor(part, 8);
            part += __shfl_xor(part, 4);
            part += __shfl_xor(part, 2);
            part += __shfl_xor(part, 1);
            if (lq == 0 && ok) {
                const float s = part * 0.125f;
                scb[pos] = (s > 0.0f) ? s + pbrow[j] : -FLT_MAX;
            }
        }

        // ---- softmax (wave shuffle reductions, no barriers) ----
        float m = -FLT_MAX;
        for (int pos = lane; pos < ncols; pos += 64) m = fmaxf(m, scb[pos]);
#pragma unroll
        for (int d = 32; d; d >>= 1) m = fmaxf(m, __shfl_xor(m, d));

        float lsum = 0.f;
        for (int pos = lane; pos < ncols; pos += 64) {
            const float p = expf(scb[pos] - m);
            scb[pos] = p;
            lsum += p;
        }
#pragma unroll
        for (int d = 32; d; d >>= 1) lsum += __shfl_xor(lsum, d);
        const float inv = 1.0f / lsum;

        // ---- PV: same 16x4 geometry, float4 V loads, no branches ----
        float4 acc = make_float4(0.f, 0.f, 0.f, 0.f);
        base = 0;
#pragma unroll 4
        for (; base + 4 <= ncols; base += 4) {
            const int pos = base + g;
            const int j = (extra && pos == 0) ? 0 : lo + pos - extra;
            const float p = scb[pos];                   // LDS broadcast
            const float4 vv = *(const float4*)(vbase + (size_t)j * DHD + lq * 4);
            acc.x += p * vv.x; acc.y += p * vv.y;
            acc.z += p * vv.z; acc.w += p * vv.w;
        }
        if (base < ncols) {                             // tail quad
            const int pos = base + g;
            float p = 0.f;
            int j = lo;
            if (pos < ncols) {
                p = scb[pos];
                j = (extra && pos == 0) ? 0 : lo + pos - extra;
            }
            const float4 vv = *(const float4*)(vbase + (size_t)j * DHD + lq * 4);
            acc.x += p * vv.x; acc.y += p * vv.y;
            acc.z += p * vv.z; acc.w += p * vv.w;
        }

        // reduce across the 4 column-groups (pairing == ((a0+a1)+(a2+a3)))
        acc.x += __shfl_xor(acc.x, 16); acc.y += __shfl_xor(acc.y, 16);
        acc.z += __shfl_xor(acc.z, 16); acc.w += __shfl_xor(acc.w, 16);
        acc.x += __shfl_xor(acc.x, 32); acc.y += __shfl_xor(acc.y, 32);
        acc.z += __shfl_xor(acc.z, 32); acc.w += __shfl_xor(acc.w, 32);

        if (g == 0) {
            float4 o = make_float4(acc.x * inv, acc.y * inv,
                                   acc.z * inv, acc.w * inv);
            *(float4*)(attn_out + ((size_t)(b * LL + i)) * EE + h * DHD + lq * 4) = o;
        }
    }
}

extern "C" void kernel_launch(void* const* d_in, const int* in_sizes, int n_in,
                              void* d_out, int out_size, void* d_ws, size_t ws_size,
                              hipStream_t stream) {
    const float* x        = (const float*)d_in[0];
    const float* pos_bias = (const float*)d_in[1];
    const float* Wq = (const float*)d_in[2];
    const float* bq = (const float*)d_in[3];
    const float* Wk = (const float*)d_in[4];
    const float* bk = (const float*)d_in[5];
    const float* Wv = (const float*)d_in[6];
    const float* bv = (const float*)d_in[7];
    const float* Wo = (const float*)d_in[8];
    const float* bo = (const float*)d_in[9];
    float* out = (float*)d_out;

    const size_t QKV = (size_t)BB * HH * LL * DHD;
    float* ws   = (float*)d_ws;
    float* q    = ws;
    float* k    = ws + QKV;
    float* v    = ws + 2 * QKV;
    float* attn = ws + 3 * QKV;                 // [B, L, E]

    dim3 blk(256);
    dim3 g1(EE / 128, (BB * LL) / 128);
    gemm_nt_f32<<<g1, blk, 0, stream>>>(x, Wq, bq, q, 1);
    gemm_nt_f32<<<g1, blk, 0, stream>>>(x, Wk, bk, k, 1);
    gemm_nt_f32<<<g1, blk, 0, stream>>>(x, Wv, bv, v, 1);

    attn_wave2<<<dim3((LL / 16) * HH * BB), 256, 0, stream>>>(q, k, v, pos_bias, attn);

    gemm_nt_f32<<<g1, blk, 0, stream>>>(attn, Wo, bo, out, 0);
}

// Round 7
// 804.339 us; speedup vs baseline: 2.4926x; 1.3149x over previous
//
#include <hip/hip_runtime.h>
#include <float.h>

#define BB 2
#define LL 2048
#define EE 1024
#define HH 16
#define DHD 64
#define WIN 128

typedef __attribute__((ext_vector_type(8))) short short8v;   // 8 bf16 (4 VGPR)
typedef __attribute__((ext_vector_type(4))) float f32x4;

static __device__ __forceinline__ unsigned short f2bf(float f) {
    union { float f; unsigned int u; } x{f};
    unsigned int r = (x.u + 0x7FFFu + ((x.u >> 16) & 1u)) >> 16;   // RNE
    return (unsigned short)r;
}

// ---------------- f32 GEMM: out = A @ W^T + bias (Q/K projections) ---------
// MUST stay f32: scores gate on s>0; bf16 here flips gates past threshold.
__global__ __launch_bounds__(256) void gemm_nt_f32(
    const float* __restrict__ A, const float* __restrict__ W,
    const float* __restrict__ bias, float* __restrict__ dst, int qkv_layout)
{
    __shared__ float As[2][16][132];
    __shared__ float Bs[2][16][132];
    const int tid = threadIdx.x;
    const int tx = tid & 15, ty = tid >> 4;
    const int row0 = blockIdx.y * 128, col0 = blockIdx.x * 128;
    const int lr = tid >> 2;
    const int lc = (tid & 3) * 4;

    float acc[8][8];
#pragma unroll
    for (int i = 0; i < 8; i++)
#pragma unroll
        for (int j = 0; j < 8; j++) acc[i][j] = 0.f;

#pragma unroll
    for (int it = 0; it < 2; it++) {
        const int r = lr + it * 64;
        float4 a = *(const float4*)&A[(size_t)(row0 + r) * EE + lc];
        As[0][lc + 0][r] = a.x; As[0][lc + 1][r] = a.y;
        As[0][lc + 2][r] = a.z; As[0][lc + 3][r] = a.w;
        float4 b = *(const float4*)&W[(size_t)(col0 + r) * EE + lc];
        Bs[0][lc + 0][r] = b.x; Bs[0][lc + 1][r] = b.y;
        Bs[0][lc + 2][r] = b.z; Bs[0][lc + 3][r] = b.w;
    }
    __syncthreads();

    int cur = 0;
    for (int t = 0; t < EE / 16; t++) {
        float4 pa[2], pb[2];
        const bool more = (t + 1) < EE / 16;
        if (more) {
            const int k0 = (t + 1) * 16;
#pragma unroll
            for (int it = 0; it < 2; it++) {
                const int r = lr + it * 64;
                pa[it] = *(const float4*)&A[(size_t)(row0 + r) * EE + k0 + lc];
                pb[it] = *(const float4*)&W[(size_t)(col0 + r) * EE + k0 + lc];
            }
        }
#pragma unroll
        for (int kk = 0; kk < 16; kk++) {
            float4 a0 = *(const float4*)&As[cur][kk][ty * 8];
            float4 a1 = *(const float4*)&As[cur][kk][ty * 8 + 4];
            float4 b0 = *(const float4*)&Bs[cur][kk][tx * 8];
            float4 b1 = *(const float4*)&Bs[cur][kk][tx * 8 + 4];
            float av[8] = {a0.x, a0.y, a0.z, a0.w, a1.x, a1.y, a1.z, a1.w};
            float bv[8] = {b0.x, b0.y, b0.z, b0.w, b1.x, b1.y, b1.z, b1.w};
#pragma unroll
            for (int i = 0; i < 8; i++)
#pragma unroll
                for (int j = 0; j < 8; j++) acc[i][j] += av[i] * bv[j];
        }
        if (more) {
            const int nb = cur ^ 1;
#pragma unroll
            for (int it = 0; it < 2; it++) {
                const int r = lr + it * 64;
                As[nb][lc + 0][r] = pa[it].x; As[nb][lc + 1][r] = pa[it].y;
                As[nb][lc + 2][r] = pa[it].z; As[nb][lc + 3][r] = pa[it].w;
                Bs[nb][lc + 0][r] = pb[it].x; Bs[nb][lc + 1][r] = pb[it].y;
                Bs[nb][lc + 2][r] = pb[it].z; Bs[nb][lc + 3][r] = pb[it].w;
            }
        }
        __syncthreads();
        cur ^= 1;
    }

#pragma unroll
    for (int i = 0; i < 8; i++) {
        const int m = row0 + ty * 8 + i;
#pragma unroll
        for (int j = 0; j < 8; j++) {
            const int n = col0 + tx * 8 + j;
            const float val = acc[i][j] + bias[n];
            if (qkv_layout) {
                const int b = m >> 11, l = m & (LL - 1);
                const int h = n >> 6, d = n & 63;
                dst[((size_t)(b * HH + h) * LL + l) * DHD + d] = val;
            } else {
                dst[(size_t)m * EE + n] = val;
            }
        }
    }
}

// ---------------- bf16 MFMA GEMM: out = A @ W^T + bias (V-proj, out-proj) --
// Inputs f32, cast to bf16 (RNE) during staging; f32 accumulate via
// mfma_f32_16x16x32_bf16. 128x128 tile, BK=32, 4 waves x (64x64) each.
// LDS rows padded to 40 ushorts (5 x 16B chunks) -> banks spread on b128 read.
__global__ __launch_bounds__(256) void gemm_nt_bf16(
    const float* __restrict__ A, const float* __restrict__ W,
    const float* __restrict__ bias, float* __restrict__ dst, int qkv_layout)
{
    __shared__ unsigned short Asm[2][128 * 40];
    __shared__ unsigned short Bsm[2][128 * 40];

    const int tid = threadIdx.x;
    const int w = tid >> 6;                 // wave 0..3
    const int lane = tid & 63;
    const int wr = w >> 1, wc = w & 1;      // wave tile: (wr*64, wc*64)
    const int lr16 = lane & 15, kg = lane >> 4;
    const int row0 = blockIdx.y * 128, col0 = blockIdx.x * 128;

    // staging mapping: thread t -> row = t>>1 (0..127), half = t&1 (k 16-span)
    const int srow = tid >> 1, shalf = tid & 1;

    f32x4 acc[4][4];
#pragma unroll
    for (int i = 0; i < 4; i++)
#pragma unroll
        for (int j = 0; j < 4; j++) acc[i][j] = (f32x4){0.f, 0.f, 0.f, 0.f};

    const float* arow = A + (size_t)(row0 + srow) * EE + shalf * 16;
    const float* brow = W + (size_t)(col0 + srow) * EE + shalf * 16;
    const int sbase = srow * 40 + shalf * 16;

    // stage tile 0
    {
        float4 fa[4], fb[4];
#pragma unroll
        for (int c = 0; c < 4; c++) {
            fa[c] = *(const float4*)(arow + c * 4);
            fb[c] = *(const float4*)(brow + c * 4);
        }
        unsigned short ua[16], ub[16];
#pragma unroll
        for (int c = 0; c < 4; c++) {
            ua[c*4+0] = f2bf(fa[c].x); ua[c*4+1] = f2bf(fa[c].y);
            ua[c*4+2] = f2bf(fa[c].z); ua[c*4+3] = f2bf(fa[c].w);
            ub[c*4+0] = f2bf(fb[c].x); ub[c*4+1] = f2bf(fb[c].y);
            ub[c*4+2] = f2bf(fb[c].z); ub[c*4+3] = f2bf(fb[c].w);
        }
        *(short8v*)&Asm[0][sbase + 0] = *(short8v*)&ua[0];
        *(short8v*)&Asm[0][sbase + 8] = *(short8v*)&ua[8];
        *(short8v*)&Bsm[0][sbase + 0] = *(short8v*)&ub[0];
        *(short8v*)&Bsm[0][sbase + 8] = *(short8v*)&ub[8];
    }
    __syncthreads();

    int cur = 0;
    for (int t = 0; t < EE / 32; t++) {
        float4 fa[4], fb[4];
        const bool more = (t + 1) < EE / 32;
        if (more) {
            const int k0 = (t + 1) * 32;
#pragma unroll
            for (int c = 0; c < 4; c++) {
                fa[c] = *(const float4*)(arow + k0 + c * 4);
                fb[c] = *(const float4*)(brow + k0 + c * 4);
            }
        }

        short8v afr[4], bfr[4];
#pragma unroll
        for (int mr = 0; mr < 4; mr++)
            afr[mr] = *(const short8v*)&Asm[cur][(wr*64 + mr*16 + lr16)*40 + kg*8];
#pragma unroll
        for (int nr = 0; nr < 4; nr++)
            bfr[nr] = *(const short8v*)&Bsm[cur][(wc*64 + nr*16 + lr16)*40 + kg*8];
#pragma unroll
        for (int mr = 0; mr < 4; mr++)
#pragma unroll
            for (int nr = 0; nr < 4; nr++)
                acc[mr][nr] = __builtin_amdgcn_mfma_f32_16x16x32_bf16(
                    afr[mr], bfr[nr], acc[mr][nr], 0, 0, 0);

        if (more) {
            const int nb = cur ^ 1;
            unsigned short ua[16], ub[16];
#pragma unroll
            for (int c = 0; c < 4; c++) {
                ua[c*4+0] = f2bf(fa[c].x); ua[c*4+1] = f2bf(fa[c].y);
                ua[c*4+2] = f2bf(fa[c].z); ua[c*4+3] = f2bf(fa[c].w);
                ub[c*4+0] = f2bf(fb[c].x); ub[c*4+1] = f2bf(fb[c].y);
                ub[c*4+2] = f2bf(fb[c].z); ub[c*4+3] = f2bf(fb[c].w);
            }
            *(short8v*)&Asm[nb][sbase + 0] = *(short8v*)&ua[0];
            *(short8v*)&Asm[nb][sbase + 8] = *(short8v*)&ua[8];
            *(short8v*)&Bsm[nb][sbase + 0] = *(short8v*)&ub[0];
            *(short8v*)&Bsm[nb][sbase + 8] = *(short8v*)&ub[8];
        }
        __syncthreads();
        cur ^= 1;
    }

    // epilogue: C/D layout col = lane&15, row = (lane>>4)*4 + reg  [m89]
#pragma unroll
    for (int mr = 0; mr < 4; mr++) {
#pragma unroll
        for (int nr = 0; nr < 4; nr++) {
            const int n = col0 + wc * 64 + nr * 16 + lr16;
            const float bb = bias[n];
#pragma unroll
            for (int j = 0; j < 4; j++) {
                const int m = row0 + wr * 64 + mr * 16 + kg * 4 + j;
                const float val = acc[mr][nr][j] + bb;
                if (qkv_layout) {
                    const int b = m >> 11, l = m & (LL - 1);
                    const int h = n >> 6, d = n & 63;
                    dst[((size_t)(b * HH + h) * LL + l) * DHD + d] = val;
                } else {
                    dst[(size_t)m * EE + n] = val;
                }
            }
        }
    }
}

// ---------------- Wave-per-row windowed sparse attention, XCD-local --------
__global__ __launch_bounds__(256) void attn_wave2(
    const float* __restrict__ q, const float* __restrict__ k,
    const float* __restrict__ v, const float* __restrict__ pos_bias,
    float* __restrict__ attn_out)
{
    const int bid = blockIdx.x;
    const int head = bid & 31;         // b*16+h
    const int chunk = bid >> 5;
    const int b = head >> 4;
    const int h = head & 15;
    const int i0 = chunk * 16;
    const int tid = threadIdx.x;
    const int w = tid >> 6;            // wave 0..3
    const int lane = tid & 63;
    const int g = lane >> 4;           // column slot 0..3
    const int lq = lane & 15;          // dim quad 0..15

    __shared__ float sc_w[4][288];     // per-wave windowed score buffer
    __shared__ float sc_d[2048];       // dense buffer (row 0 only)

    const size_t bh = (size_t)(b * HH + h) * LL;
    const float* kbase = k + bh * DHD;
    const float* vbase = v + bh * DHD;

    for (int r = 0; r < 4; r++) {
        const int i = i0 + w * 4 + r;
        float* scb = (i == 0) ? sc_d : sc_w[w];

        int lo, ncols, extra;
        if (i == 0) { lo = 0; extra = 0; ncols = LL; }
        else {
            lo = (i - WIN > 0) ? i - WIN : 0;
            const int hi = (i + WIN < LL - 1) ? i + WIN : LL - 1;
            extra = (lo > 0) ? 1 : 0;          // column 0 prepended
            ncols = hi - lo + 1 + extra;
        }

        const float4 q4 = *(const float4*)(q + (bh + i) * DHD + lq * 4);
        const float* pbrow = pos_bias + (size_t)i * LL;

        int base = 0;
#pragma unroll 2
        for (; base + 4 <= ncols; base += 4) {
            const int pos = base + g;
            const int j = (extra && pos == 0) ? 0 : lo + pos - extra;
            const float4 kv = *(const float4*)(kbase + (size_t)j * DHD + lq * 4);
            float part = q4.x * kv.x + q4.y * kv.y + q4.z * kv.z + q4.w * kv.w;
            part += __shfl_xor(part, 8);
            part += __shfl_xor(part, 4);
            part += __shfl_xor(part, 2);
            part += __shfl_xor(part, 1);
            if (lq == 0) {
                const float s = part * 0.125f;          // 1/sqrt(64)
                scb[pos] = (s > 0.0f) ? s + pbrow[j] : -FLT_MAX;
            }
        }
        if (base < ncols) {                             // tail quad
            const int pos = base + g;
            const bool ok = pos < ncols;
            int j = lo;
            float part = 0.f;
            if (ok) {
                j = (extra && pos == 0) ? 0 : lo + pos - extra;
                const float4 kv = *(const float4*)(kbase + (size_t)j * DHD + lq * 4);
                part = q4.x * kv.x + q4.y * kv.y + q4.z * kv.z + q4.w * kv.w;
            }
            part += __shfl_xor(part, 8);
            part += __shfl_xor(part, 4);
            part += __shfl_xor(part, 2);
            part += __shfl_xor(part, 1);
            if (lq == 0 && ok) {
                const float s = part * 0.125f;
                scb[pos] = (s > 0.0f) ? s + pbrow[j] : -FLT_MAX;
            }
        }

        float m = -FLT_MAX;
        for (int pos = lane; pos < ncols; pos += 64) m = fmaxf(m, scb[pos]);
#pragma unroll
        for (int d = 32; d; d >>= 1) m = fmaxf(m, __shfl_xor(m, d));

        float lsum = 0.f;
        for (int pos = lane; pos < ncols; pos += 64) {
            const float p = expf(scb[pos] - m);
            scb[pos] = p;
            lsum += p;
        }
#pragma unroll
        for (int d = 32; d; d >>= 1) lsum += __shfl_xor(lsum, d);
        const float inv = 1.0f / lsum;

        float4 acc = make_float4(0.f, 0.f, 0.f, 0.f);
        base = 0;
#pragma unroll 4
        for (; base + 4 <= ncols; base += 4) {
            const int pos = base + g;
            const int j = (extra && pos == 0) ? 0 : lo + pos - extra;
            const float p = scb[pos];                   // LDS broadcast
            const float4 vv = *(const float4*)(vbase + (size_t)j * DHD + lq * 4);
            acc.x += p * vv.x; acc.y += p * vv.y;
            acc.z += p * vv.z; acc.w += p * vv.w;
        }
        if (base < ncols) {                             // tail quad
            const int pos = base + g;
            float p = 0.f;
            int j = lo;
            if (pos < ncols) {
                p = scb[pos];
                j = (extra && pos == 0) ? 0 : lo + pos - extra;
            }
            const float4 vv = *(const float4*)(vbase + (size_t)j * DHD + lq * 4);
            acc.x += p * vv.x; acc.y += p * vv.y;
            acc.z += p * vv.z; acc.w += p * vv.w;
        }

        acc.x += __shfl_xor(acc.x, 16); acc.y += __shfl_xor(acc.y, 16);
        acc.z += __shfl_xor(acc.z, 16); acc.w += __shfl_xor(acc.w, 16);
        acc.x += __shfl_xor(acc.x, 32); acc.y += __shfl_xor(acc.y, 32);
        acc.z += __shfl_xor(acc.z, 32); acc.w += __shfl_xor(acc.w, 32);

        if (g == 0) {
            float4 o = make_float4(acc.x * inv, acc.y * inv,
                                   acc.z * inv, acc.w * inv);
            *(float4*)(attn_out + ((size_t)(b * LL + i)) * EE + h * DHD + lq * 4) = o;
        }
    }
}

extern "C" void kernel_launch(void* const* d_in, const int* in_sizes, int n_in,
                              void* d_out, int out_size, void* d_ws, size_t ws_size,
                              hipStream_t stream) {
    const float* x        = (const float*)d_in[0];
    const float* pos_bias = (const float*)d_in[1];
    const float* Wq = (const float*)d_in[2];
    const float* bq = (const float*)d_in[3];
    const float* Wk = (const float*)d_in[4];
    const float* bk = (const float*)d_in[5];
    const float* Wv = (const float*)d_in[6];
    const float* bv = (const float*)d_in[7];
    const float* Wo = (const float*)d_in[8];
    const float* bo = (const float*)d_in[9];
    float* out = (float*)d_out;

    const size_t QKV = (size_t)BB * HH * LL * DHD;
    float* ws   = (float*)d_ws;
    float* q    = ws;
    float* k    = ws + QKV;
    float* v    = ws + 2 * QKV;
    float* attn = ws + 3 * QKV;                 // [B, L, E]

    dim3 blk(256);
    dim3 g1(EE / 128, (BB * LL) / 128);
    gemm_nt_f32<<<g1, blk, 0, stream>>>(x, Wq, bq, q, 1);
    gemm_nt_f32<<<g1, blk, 0, stream>>>(x, Wk, bk, k, 1);
    gemm_nt_bf16<<<g1, blk, 0, stream>>>(x, Wv, bv, v, 1);

    attn_wave2<<<dim3((LL / 16) * HH * BB), 256, 0, stream>>>(q, k, v, pos_bias, attn);

    gemm_nt_bf16<<<g1, blk, 0, stream>>>(attn, Wo, bo, out, 0);
}

// Round 8
// 485.316 us; speedup vs baseline: 4.1312x; 1.6574x over previous
//
#include <hip/hip_runtime.h>
#include <float.h>

#define BB 2
#define LL 2048
#define EE 1024
#define HH 16
#define DHD 64
#define WIN 128

typedef __attribute__((ext_vector_type(8))) short short8v;       // 8 bf16
typedef __attribute__((ext_vector_type(8))) _Float16 half8v;     // 8 fp16
typedef __attribute__((ext_vector_type(4))) float f32x4;

static __device__ __forceinline__ unsigned short f2bf(float f) {
    union { float f; unsigned int u; } x{f};
    unsigned int r = (x.u + 0x7FFFu + ((x.u >> 16) & 1u)) >> 16;   // RNE
    return (unsigned short)r;
}

static __device__ __forceinline__ void f2h_split(float f, unsigned short& hi,
                                                 unsigned short& lo) {
    _Float16 h = (_Float16)f;          // RNE
    _Float16 l = (_Float16)(f - (float)h);
    union { _Float16 h; unsigned short u; } uh, ul;
    uh.h = h; ul.h = l;
    hi = uh.u; lo = ul.u;
}

// ---------------- fp16-split MFMA GEMM (Q/K projections) -------------------
// a = hi + lo in fp16; C = Ah*Bh + Ah*Bl + Al*Bh (f32 accum). Dropped lolo
// term ~6e-8 rel => score error in the f32-rounding class; gates safe.
// 128x128 tile, BK=32, single-buffered LDS (40 KB), 4 waves x 64x64.
__global__ __launch_bounds__(256) void gemm_nt_f16x2(
    const float* __restrict__ A, const float* __restrict__ W,
    const float* __restrict__ bias, float* __restrict__ dst, int qkv_layout)
{
    __shared__ unsigned short Ah[128 * 40], Al[128 * 40];
    __shared__ unsigned short Bh[128 * 40], Bl[128 * 40];

    const int tid = threadIdx.x;
    const int w = tid >> 6, lane = tid & 63;
    const int wr = w >> 1, wc = w & 1;
    const int lr16 = lane & 15, kg = lane >> 4;
    const int row0 = blockIdx.y * 128, col0 = blockIdx.x * 128;
    const int srow = tid >> 1, shalf = tid & 1;
    const int sbase = srow * 40 + shalf * 16;

    const float* arow = A + (size_t)(row0 + srow) * EE + shalf * 16;
    const float* brow = W + (size_t)(col0 + srow) * EE + shalf * 16;

    f32x4 acc[4][4];
#pragma unroll
    for (int i = 0; i < 4; i++)
#pragma unroll
        for (int j = 0; j < 4; j++) acc[i][j] = (f32x4){0.f, 0.f, 0.f, 0.f};

    for (int t = 0; t < EE / 32; t++) {
        const int k0 = t * 32;
        float4 fa[4], fb[4];
#pragma unroll
        for (int c = 0; c < 4; c++) {
            fa[c] = *(const float4*)(arow + k0 + c * 4);
            fb[c] = *(const float4*)(brow + k0 + c * 4);
        }
        unsigned short ah[16], al[16], bh[16], bl[16];
#pragma unroll
        for (int c = 0; c < 4; c++) {
            f2h_split(fa[c].x, ah[c*4+0], al[c*4+0]);
            f2h_split(fa[c].y, ah[c*4+1], al[c*4+1]);
            f2h_split(fa[c].z, ah[c*4+2], al[c*4+2]);
            f2h_split(fa[c].w, ah[c*4+3], al[c*4+3]);
            f2h_split(fb[c].x, bh[c*4+0], bl[c*4+0]);
            f2h_split(fb[c].y, bh[c*4+1], bl[c*4+1]);
            f2h_split(fb[c].z, bh[c*4+2], bl[c*4+2]);
            f2h_split(fb[c].w, bh[c*4+3], bl[c*4+3]);
        }
        __syncthreads();                       // prev iter's reads done
        *(short8v*)&Ah[sbase + 0] = *(short8v*)&ah[0];
        *(short8v*)&Ah[sbase + 8] = *(short8v*)&ah[8];
        *(short8v*)&Al[sbase + 0] = *(short8v*)&al[0];
        *(short8v*)&Al[sbase + 8] = *(short8v*)&al[8];
        *(short8v*)&Bh[sbase + 0] = *(short8v*)&bh[0];
        *(short8v*)&Bh[sbase + 8] = *(short8v*)&bh[8];
        *(short8v*)&Bl[sbase + 0] = *(short8v*)&bl[0];
        *(short8v*)&Bl[sbase + 8] = *(short8v*)&bl[8];
        __syncthreads();                       // writes visible

        half8v afh[4], afl[4], bfh[4], bfl[4];
#pragma unroll
        for (int mr = 0; mr < 4; mr++) {
            const int off = (wr * 64 + mr * 16 + lr16) * 40 + kg * 8;
            afh[mr] = *(const half8v*)&Ah[off];
            afl[mr] = *(const half8v*)&Al[off];
        }
#pragma unroll
        for (int nr = 0; nr < 4; nr++) {
            const int off = (wc * 64 + nr * 16 + lr16) * 40 + kg * 8;
            bfh[nr] = *(const half8v*)&Bh[off];
            bfl[nr] = *(const half8v*)&Bl[off];
        }
#pragma unroll
        for (int mr = 0; mr < 4; mr++)
#pragma unroll
            for (int nr = 0; nr < 4; nr++) {
                acc[mr][nr] = __builtin_amdgcn_mfma_f32_16x16x32_f16(
                    afl[mr], bfh[nr], acc[mr][nr], 0, 0, 0);
                acc[mr][nr] = __builtin_amdgcn_mfma_f32_16x16x32_f16(
                    afh[mr], bfl[nr], acc[mr][nr], 0, 0, 0);
                acc[mr][nr] = __builtin_amdgcn_mfma_f32_16x16x32_f16(
                    afh[mr], bfh[nr], acc[mr][nr], 0, 0, 0);
            }
    }

#pragma unroll
    for (int mr = 0; mr < 4; mr++) {
#pragma unroll
        for (int nr = 0; nr < 4; nr++) {
            const int n = col0 + wc * 64 + nr * 16 + lr16;
            const float bb = bias[n];
#pragma unroll
            for (int j = 0; j < 4; j++) {
                const int m = row0 + wr * 64 + mr * 16 + kg * 4 + j;
                const float val = acc[mr][nr][j] + bb;
                if (qkv_layout) {
                    const int b = m >> 11, l = m & (LL - 1);
                    const int hh = n >> 6, d = n & 63;
                    dst[((size_t)(b * HH + hh) * LL + l) * DHD + d] = val;
                } else {
                    dst[(size_t)m * EE + n] = val;
                }
            }
        }
    }
}

// ---------------- bf16 MFMA GEMM (V-proj, out-proj; smooth paths) ----------
__global__ __launch_bounds__(256) void gemm_nt_bf16(
    const float* __restrict__ A, const float* __restrict__ W,
    const float* __restrict__ bias, float* __restrict__ dst, int qkv_layout)
{
    __shared__ unsigned short Asm[2][128 * 40];
    __shared__ unsigned short Bsm[2][128 * 40];

    const int tid = threadIdx.x;
    const int w = tid >> 6;
    const int lane = tid & 63;
    const int wr = w >> 1, wc = w & 1;
    const int lr16 = lane & 15, kg = lane >> 4;
    const int row0 = blockIdx.y * 128, col0 = blockIdx.x * 128;
    const int srow = tid >> 1, shalf = tid & 1;

    f32x4 acc[4][4];
#pragma unroll
    for (int i = 0; i < 4; i++)
#pragma unroll
        for (int j = 0; j < 4; j++) acc[i][j] = (f32x4){0.f, 0.f, 0.f, 0.f};

    const float* arow = A + (size_t)(row0 + srow) * EE + shalf * 16;
    const float* brow = W + (size_t)(col0 + srow) * EE + shalf * 16;
    const int sbase = srow * 40 + shalf * 16;

    {
        float4 fa[4], fb[4];
#pragma unroll
        for (int c = 0; c < 4; c++) {
            fa[c] = *(const float4*)(arow + c * 4);
            fb[c] = *(const float4*)(brow + c * 4);
        }
        unsigned short ua[16], ub[16];
#pragma unroll
        for (int c = 0; c < 4; c++) {
            ua[c*4+0] = f2bf(fa[c].x); ua[c*4+1] = f2bf(fa[c].y);
            ua[c*4+2] = f2bf(fa[c].z); ua[c*4+3] = f2bf(fa[c].w);
            ub[c*4+0] = f2bf(fb[c].x); ub[c*4+1] = f2bf(fb[c].y);
            ub[c*4+2] = f2bf(fb[c].z); ub[c*4+3] = f2bf(fb[c].w);
        }
        *(short8v*)&Asm[0][sbase + 0] = *(short8v*)&ua[0];
        *(short8v*)&Asm[0][sbase + 8] = *(short8v*)&ua[8];
        *(short8v*)&Bsm[0][sbase + 0] = *(short8v*)&ub[0];
        *(short8v*)&Bsm[0][sbase + 8] = *(short8v*)&ub[8];
    }
    __syncthreads();

    int cur = 0;
    for (int t = 0; t < EE / 32; t++) {
        float4 fa[4], fb[4];
        const bool more = (t + 1) < EE / 32;
        if (more) {
            const int k0 = (t + 1) * 32;
#pragma unroll
            for (int c = 0; c < 4; c++) {
                fa[c] = *(const float4*)(arow + k0 + c * 4);
                fb[c] = *(const float4*)(brow + k0 + c * 4);
            }
        }

        short8v afr[4], bfr[4];
#pragma unroll
        for (int mr = 0; mr < 4; mr++)
            afr[mr] = *(const short8v*)&Asm[cur][(wr*64 + mr*16 + lr16)*40 + kg*8];
#pragma unroll
        for (int nr = 0; nr < 4; nr++)
            bfr[nr] = *(const short8v*)&Bsm[cur][(wc*64 + nr*16 + lr16)*40 + kg*8];
#pragma unroll
        for (int mr = 0; mr < 4; mr++)
#pragma unroll
            for (int nr = 0; nr < 4; nr++)
                acc[mr][nr] = __builtin_amdgcn_mfma_f32_16x16x32_bf16(
                    afr[mr], bfr[nr], acc[mr][nr], 0, 0, 0);

        if (more) {
            const int nb = cur ^ 1;
            unsigned short ua[16], ub[16];
#pragma unroll
            for (int c = 0; c < 4; c++) {
                ua[c*4+0] = f2bf(fa[c].x); ua[c*4+1] = f2bf(fa[c].y);
                ua[c*4+2] = f2bf(fa[c].z); ua[c*4+3] = f2bf(fa[c].w);
                ub[c*4+0] = f2bf(fb[c].x); ub[c*4+1] = f2bf(fb[c].y);
                ub[c*4+2] = f2bf(fb[c].z); ub[c*4+3] = f2bf(fb[c].w);
            }
            *(short8v*)&Asm[nb][sbase + 0] = *(short8v*)&ua[0];
            *(short8v*)&Asm[nb][sbase + 8] = *(short8v*)&ua[8];
            *(short8v*)&Bsm[nb][sbase + 0] = *(short8v*)&ub[0];
            *(short8v*)&Bsm[nb][sbase + 8] = *(short8v*)&ub[8];
        }
        __syncthreads();
        cur ^= 1;
    }

#pragma unroll
    for (int mr = 0; mr < 4; mr++) {
#pragma unroll
        for (int nr = 0; nr < 4; nr++) {
            const int n = col0 + wc * 64 + nr * 16 + lr16;
            const float bb = bias[n];
#pragma unroll
            for (int j = 0; j < 4; j++) {
                const int m = row0 + wr * 64 + mr * 16 + kg * 4 + j;
                const float val = acc[mr][nr][j] + bb;
                if (qkv_layout) {
                    const int b = m >> 11, l = m & (LL - 1);
                    const int hh = n >> 6, d = n & 63;
                    dst[((size_t)(b * HH + hh) * LL + l) * DHD + d] = val;
                } else {
                    dst[(size_t)m * EE + n] = val;
                }
            }
        }
    }
}

// ------- Joint 4-row wave attention: one K/V load serves 4 query rows ------
// Block = 4 waves; wave w owns rows i0w..i0w+3 over their UNION window
// [i0w-128, i0w+131] (+col 0). Per-column dot keeps the exact 16-lane
// float4-quad + xor-butterfly structure => scores bit-identical to r7.
// Row 0 (dense, 32 instances) keeps the per-row path via scd.
__global__ __launch_bounds__(256) void attn_joint(
    const float* __restrict__ q, const float* __restrict__ k,
    const float* __restrict__ v, const float* __restrict__ pos_bias,
    float* __restrict__ attn_out)
{
    const int bid = blockIdx.x;
    const int head = bid & 31;          // b*16+h  (XCD-local: all chunks of a
    const int chunk = bid >> 5;         //  head share bid%8 -> same L2)
    const int b = head >> 4, h = head & 15;
    const int tid = threadIdx.x;
    const int w = tid >> 6, lane = tid & 63;
    const int g = lane >> 4, lq = lane & 15;
    const int i0w = chunk * 16 + w * 4;

    __shared__ float scj[4][4][264];    // [wave][row][union pos]
    __shared__ float scd[2048];         // dense row-0 buffer (wave 0, chunk 0)

    const size_t bh = (size_t)(b * HH + h) * LL;
    const float* kbase = k + bh * DHD;
    const float* vbase = v + bh * DHD;

    int lo_u = i0w - WIN; if (lo_u < 0) lo_u = 0;
    int hi_u = i0w + 3 + WIN; if (hi_u > LL - 1) hi_u = LL - 1;
    const int extra = (lo_u > 0) ? 1 : 0;
    const int ncols = hi_u - lo_u + 1 + extra;

    float4 q4[4];
#pragma unroll
    for (int r = 0; r < 4; r++)
        q4[r] = *(const float4*)(q + (bh + i0w + r) * DHD + lq * 4);

    // ---- QK: one K load -> 4 row dots ----
    for (int base = 0; base < ncols; base += 4) {
        const int pos = base + g;
        const bool inb = pos < ncols;
        int j = (extra && pos == 0) ? 0 : lo_u + pos - extra;
        if (!inb) j = lo_u;
        const float4 kv = *(const float4*)(kbase + (size_t)j * DHD + lq * 4);
        float s0 = q4[0].x*kv.x + q4[0].y*kv.y + q4[0].z*kv.z + q4[0].w*kv.w;
        float s1 = q4[1].x*kv.x + q4[1].y*kv.y + q4[1].z*kv.z + q4[1].w*kv.w;
        float s2 = q4[2].x*kv.x + q4[2].y*kv.y + q4[2].z*kv.z + q4[2].w*kv.w;
        float s3 = q4[3].x*kv.x + q4[3].y*kv.y + q4[3].z*kv.z + q4[3].w*kv.w;
        s0 += __shfl_xor(s0, 8); s0 += __shfl_xor(s0, 4);
        s0 += __shfl_xor(s0, 2); s0 += __shfl_xor(s0, 1);
        s1 += __shfl_xor(s1, 8); s1 += __shfl_xor(s1, 4);
        s1 += __shfl_xor(s1, 2); s1 += __shfl_xor(s1, 1);
        s2 += __shfl_xor(s2, 8); s2 += __shfl_xor(s2, 4);
        s2 += __shfl_xor(s2, 2); s2 += __shfl_xor(s2, 1);
        s3 += __shfl_xor(s3, 8); s3 += __shfl_xor(s3, 4);
        s3 += __shfl_xor(s3, 2); s3 += __shfl_xor(s3, 1);
        if (inb && lq < 4) {
            const int r = lq;
            const int ir = i0w + r;
            const float sv = (r == 0) ? s0 : (r == 1) ? s1 : (r == 2) ? s2 : s3;
            float outv;
            if (ir == 0) {
                outv = 0.f;                       // dense row handled separately
            } else {
                const bool allowed = (j == 0) |
                                     ((j >= ir - WIN) & (j <= ir + WIN));
                const float s = sv * 0.125f;      // 1/sqrt(64)
                outv = (allowed && s > 0.f)
                         ? s + pos_bias[(size_t)ir * LL + j] : -FLT_MAX;
            }
            scj[w][r][pos] = outv;
        }
    }

    // ---- softmax per row (wave-local) ----
    float inv0, inv1, inv2, inv3;
#pragma unroll
    for (int r = 0; r < 4; r++) {
        float m = -FLT_MAX;
        for (int pos = lane; pos < ncols; pos += 64)
            m = fmaxf(m, scj[w][r][pos]);
#pragma unroll
        for (int d = 32; d; d >>= 1) m = fmaxf(m, __shfl_xor(m, d));
        float l = 0.f;
        for (int pos = lane; pos < ncols; pos += 64) {
            const float p = expf(scj[w][r][pos] - m);
            scj[w][r][pos] = p;
            l += p;
        }
#pragma unroll
        for (int d = 32; d; d >>= 1) l += __shfl_xor(l, d);
        const float iv = 1.0f / l;
        if (r == 0) inv0 = iv; else if (r == 1) inv1 = iv;
        else if (r == 2) inv2 = iv; else inv3 = iv;
    }

    // ---- PV: one V load -> 4 row FMAs ----
    float4 a0 = make_float4(0.f,0.f,0.f,0.f), a1 = a0, a2 = a0, a3 = a0;
    for (int base = 0; base < ncols; base += 4) {
        const int pos = base + g;
        const bool inb = pos < ncols;
        int j = (extra && pos == 0) ? 0 : lo_u + pos - extra;
        if (!inb) j = lo_u;
        const float4 vv = *(const float4*)(vbase + (size_t)j * DHD + lq * 4);
        const float p0 = inb ? scj[w][0][pos] : 0.f;
        const float p1 = inb ? scj[w][1][pos] : 0.f;
        const float p2 = inb ? scj[w][2][pos] : 0.f;
        const float p3 = inb ? scj[w][3][pos] : 0.f;
        a0.x += p0*vv.x; a0.y += p0*vv.y; a0.z += p0*vv.z; a0.w += p0*vv.w;
        a1.x += p1*vv.x; a1.y += p1*vv.y; a1.z += p1*vv.z; a1.w += p1*vv.w;
        a2.x += p2*vv.x; a2.y += p2*vv.y; a2.z += p2*vv.z; a2.w += p2*vv.w;
        a3.x += p3*vv.x; a3.y += p3*vv.y; a3.z += p3*vv.z; a3.w += p3*vv.w;
    }

#pragma unroll
    for (int r = 0; r < 4; r++) {
        float4 a = (r == 0) ? a0 : (r == 1) ? a1 : (r == 2) ? a2 : a3;
        const float iv = (r == 0) ? inv0 : (r == 1) ? inv1 : (r == 2) ? inv2 : inv3;
        a.x += __shfl_xor(a.x, 16); a.y += __shfl_xor(a.y, 16);
        a.z += __shfl_xor(a.z, 16); a.w += __shfl_xor(a.w, 16);
        a.x += __shfl_xor(a.x, 32); a.y += __shfl_xor(a.y, 32);
        a.z += __shfl_xor(a.z, 32); a.w += __shfl_xor(a.w, 32);
        const int i = i0w + r;
        if (g == 0 && i != 0) {
            float4 o = make_float4(a.x*iv, a.y*iv, a.z*iv, a.w*iv);
            *(float4*)(attn_out + ((size_t)(b * LL + i)) * EE + h * DHD + lq * 4) = o;
        }
    }

    // ---- dense row 0 (only wave 0 of chunk-0 blocks; 32 instances) ----
    if (i0w == 0) {
        const float4 q0 = q4[0];
        for (int base = 0; base < LL; base += 4) {
            const int pos = base + g;
            const float4 kv = *(const float4*)(kbase + (size_t)pos * DHD + lq * 4);
            float part = q0.x*kv.x + q0.y*kv.y + q0.z*kv.z + q0.w*kv.w;
            part += __shfl_xor(part, 8); part += __shfl_xor(part, 4);
            part += __shfl_xor(part, 2); part += __shfl_xor(part, 1);
            if (lq == 0) {
                const float s = part * 0.125f;
                scd[pos] = (s > 0.f) ? s + pos_bias[pos] : -FLT_MAX;
            }
        }
        float m = -FLT_MAX;
        for (int pos = lane; pos < LL; pos += 64) m = fmaxf(m, scd[pos]);
#pragma unroll
        for (int d = 32; d; d >>= 1) m = fmaxf(m, __shfl_xor(m, d));
        float l = 0.f;
        for (int pos = lane; pos < LL; pos += 64) {
            const float p = expf(scd[pos] - m);
            scd[pos] = p;
            l += p;
        }
#pragma unroll
        for (int d = 32; d; d >>= 1) l += __shfl_xor(l, d);
        const float iv = 1.0f / l;

        float4 a = make_float4(0.f,0.f,0.f,0.f);
        for (int base = 0; base < LL; base += 4) {
            const int pos = base + g;
            const float p = scd[pos];
            const float4 vv = *(const float4*)(vbase + (size_t)pos * DHD + lq * 4);
            a.x += p*vv.x; a.y += p*vv.y; a.z += p*vv.z; a.w += p*vv.w;
        }
        a.x += __shfl_xor(a.x, 16); a.y += __shfl_xor(a.y, 16);
        a.z += __shfl_xor(a.z, 16); a.w += __shfl_xor(a.w, 16);
        a.x += __shfl_xor(a.x, 32); a.y += __shfl_xor(a.y, 32);
        a.z += __shfl_xor(a.z, 32); a.w += __shfl_xor(a.w, 32);
        if (g == 0) {
            float4 o = make_float4(a.x*iv, a.y*iv, a.z*iv, a.w*iv);
            *(float4*)(attn_out + ((size_t)(b * LL)) * EE + h * DHD + lq * 4) = o;
        }
    }
}

extern "C" void kernel_launch(void* const* d_in, const int* in_sizes, int n_in,
                              void* d_out, int out_size, void* d_ws, size_t ws_size,
                              hipStream_t stream) {
    const float* x        = (const float*)d_in[0];
    const float* pos_bias = (const float*)d_in[1];
    const float* Wq = (const float*)d_in[2];
    const float* bq = (const float*)d_in[3];
    const float* Wk = (const float*)d_in[4];
    const float* bk = (const float*)d_in[5];
    const float* Wv = (const float*)d_in[6];
    const float* bv = (const float*)d_in[7];
    const float* Wo = (const float*)d_in[8];
    const float* bo = (const float*)d_in[9];
    float* out = (float*)d_out;

    const size_t QKV = (size_t)BB * HH * LL * DHD;
    float* ws   = (float*)d_ws;
    float* q    = ws;
    float* k    = ws + QKV;
    float* v    = ws + 2 * QKV;
    float* attn = ws + 3 * QKV;                 // [B, L, E]

    dim3 blk(256);
    dim3 g1(EE / 128, (BB * LL) / 128);
    gemm_nt_f16x2<<<g1, blk, 0, stream>>>(x, Wq, bq, q, 1);
    gemm_nt_f16x2<<<g1, blk, 0, stream>>>(x, Wk, bk, k, 1);
    gemm_nt_bf16 <<<g1, blk, 0, stream>>>(x, Wv, bv, v, 1);

    attn_joint<<<dim3((LL / 16) * HH * BB), 256, 0, stream>>>(q, k, v, pos_bias, attn);

    gemm_nt_bf16<<<g1, blk, 0, stream>>>(attn, Wo, bo, out, 0);
}

// Round 9
// 369.471 us; speedup vs baseline: 5.4265x; 1.3135x over previous
//
#include <hip/hip_runtime.h>
#include <float.h>

#define BB 2
#define LL 2048
#define EE 1024
#define HH 16
#define DHD 64
#define WIN 128

typedef __attribute__((ext_vector_type(8))) short short8v;       // 8 bf16
typedef __attribute__((ext_vector_type(8))) _Float16 half8v;     // 8 fp16
typedef __attribute__((ext_vector_type(4))) float f32x4;

static __device__ __forceinline__ unsigned short f2bf(float f) {
    union { float f; unsigned int u; } x{f};
    unsigned int r = (x.u + 0x7FFFu + ((x.u >> 16) & 1u)) >> 16;   // RNE
    return (unsigned short)r;
}
static __device__ __forceinline__ float bf2f(unsigned short u) {
    union { unsigned int u; float f; } x{(unsigned int)u << 16};
    return x.f;
}
static __device__ __forceinline__ float h2f_u(unsigned short u) {
    union { unsigned short u; _Float16 h; } x{u};
    return (float)x.h;
}
static __device__ __forceinline__ void f2h_split(float f, unsigned short& hi,
                                                 unsigned short& lo) {
    _Float16 h = (_Float16)f;          // RNE
    _Float16 l = (_Float16)(f - (float)h);
    union { _Float16 h; unsigned short u; } uh, ul;
    uh.h = h; ul.h = l;
    hi = uh.u; lo = ul.u;
}

// ---------------- fp16-split MFMA GEMM (Q/K projections) -------------------
// Writes SPLIT hi/lo fp16 planes [b,h,l,d] so attention can MFMA directly.
__global__ __launch_bounds__(256) void gemm_nt_f16x2(
    const float* __restrict__ A, const float* __restrict__ W,
    const float* __restrict__ bias,
    unsigned short* __restrict__ dhi, unsigned short* __restrict__ dlo)
{
    __shared__ unsigned short Ah[128 * 40], Al[128 * 40];
    __shared__ unsigned short Bh[128 * 40], Bl[128 * 40];

    const int tid = threadIdx.x;
    const int w = tid >> 6, lane = tid & 63;
    const int wr = w >> 1, wc = w & 1;
    const int lr16 = lane & 15, kg = lane >> 4;
    const int row0 = blockIdx.y * 128, col0 = blockIdx.x * 128;
    const int srow = tid >> 1, shalf = tid & 1;
    const int sbase = srow * 40 + shalf * 16;

    const float* arow = A + (size_t)(row0 + srow) * EE + shalf * 16;
    const float* brow = W + (size_t)(col0 + srow) * EE + shalf * 16;

    f32x4 acc[4][4];
#pragma unroll
    for (int i = 0; i < 4; i++)
#pragma unroll
        for (int j = 0; j < 4; j++) acc[i][j] = (f32x4){0.f, 0.f, 0.f, 0.f};

    for (int t = 0; t < EE / 32; t++) {
        const int k0 = t * 32;
        float4 fa[4], fb[4];
#pragma unroll
        for (int c = 0; c < 4; c++) {
            fa[c] = *(const float4*)(arow + k0 + c * 4);
            fb[c] = *(const float4*)(brow + k0 + c * 4);
        }
        unsigned short ah[16], al[16], bh[16], bl[16];
#pragma unroll
        for (int c = 0; c < 4; c++) {
            f2h_split(fa[c].x, ah[c*4+0], al[c*4+0]);
            f2h_split(fa[c].y, ah[c*4+1], al[c*4+1]);
            f2h_split(fa[c].z, ah[c*4+2], al[c*4+2]);
            f2h_split(fa[c].w, ah[c*4+3], al[c*4+3]);
            f2h_split(fb[c].x, bh[c*4+0], bl[c*4+0]);
            f2h_split(fb[c].y, bh[c*4+1], bl[c*4+1]);
            f2h_split(fb[c].z, bh[c*4+2], bl[c*4+2]);
            f2h_split(fb[c].w, bh[c*4+3], bl[c*4+3]);
        }
        __syncthreads();
        *(short8v*)&Ah[sbase + 0] = *(short8v*)&ah[0];
        *(short8v*)&Ah[sbase + 8] = *(short8v*)&ah[8];
        *(short8v*)&Al[sbase + 0] = *(short8v*)&al[0];
        *(short8v*)&Al[sbase + 8] = *(short8v*)&al[8];
        *(short8v*)&Bh[sbase + 0] = *(short8v*)&bh[0];
        *(short8v*)&Bh[sbase + 8] = *(short8v*)&bh[8];
        *(short8v*)&Bl[sbase + 0] = *(short8v*)&bl[0];
        *(short8v*)&Bl[sbase + 8] = *(short8v*)&bl[8];
        __syncthreads();

        half8v afh[4], afl[4], bfh[4], bfl[4];
#pragma unroll
        for (int mr = 0; mr < 4; mr++) {
            const int off = (wr * 64 + mr * 16 + lr16) * 40 + kg * 8;
            afh[mr] = *(const half8v*)&Ah[off];
            afl[mr] = *(const half8v*)&Al[off];
        }
#pragma unroll
        for (int nr = 0; nr < 4; nr++) {
            const int off = (wc * 64 + nr * 16 + lr16) * 40 + kg * 8;
            bfh[nr] = *(const half8v*)&Bh[off];
            bfl[nr] = *(const half8v*)&Bl[off];
        }
#pragma unroll
        for (int mr = 0; mr < 4; mr++)
#pragma unroll
            for (int nr = 0; nr < 4; nr++) {
                acc[mr][nr] = __builtin_amdgcn_mfma_f32_16x16x32_f16(
                    afl[mr], bfh[nr], acc[mr][nr], 0, 0, 0);
                acc[mr][nr] = __builtin_amdgcn_mfma_f32_16x16x32_f16(
                    afh[mr], bfl[nr], acc[mr][nr], 0, 0, 0);
                acc[mr][nr] = __builtin_amdgcn_mfma_f32_16x16x32_f16(
                    afh[mr], bfh[nr], acc[mr][nr], 0, 0, 0);
            }
    }

#pragma unroll
    for (int mr = 0; mr < 4; mr++) {
#pragma unroll
        for (int nr = 0; nr < 4; nr++) {
            const int n = col0 + wc * 64 + nr * 16 + lr16;
            const float bv = bias[n];
#pragma unroll
            for (int j = 0; j < 4; j++) {
                const int m = row0 + wr * 64 + mr * 16 + kg * 4 + j;
                const float val = acc[mr][nr][j] + bv;
                const int bi = m >> 11, l = m & (LL - 1);
                const int hh = n >> 6, d = n & 63;
                const size_t o = ((size_t)(bi * HH + hh) * LL + l) * DHD + d;
                unsigned short hu, lu;
                f2h_split(val, hu, lu);
                dhi[o] = hu; dlo[o] = lu;
            }
        }
    }
}

// ---------------- bf16 MFMA GEMM (V-proj -> bf16 V^T, out-proj -> f32) -----
__global__ __launch_bounds__(256) void gemm_nt_bf16(
    const float* __restrict__ A, const float* __restrict__ W,
    const float* __restrict__ bias, float* __restrict__ dstf,
    unsigned short* __restrict__ dstv, int mode)
{
    __shared__ unsigned short Asm[2][128 * 40];
    __shared__ unsigned short Bsm[2][128 * 40];

    const int tid = threadIdx.x;
    const int w = tid >> 6;
    const int lane = tid & 63;
    const int wr = w >> 1, wc = w & 1;
    const int lr16 = lane & 15, kg = lane >> 4;
    const int row0 = blockIdx.y * 128, col0 = blockIdx.x * 128;
    const int srow = tid >> 1, shalf = tid & 1;

    f32x4 acc[4][4];
#pragma unroll
    for (int i = 0; i < 4; i++)
#pragma unroll
        for (int j = 0; j < 4; j++) acc[i][j] = (f32x4){0.f, 0.f, 0.f, 0.f};

    const float* arow = A + (size_t)(row0 + srow) * EE + shalf * 16;
    const float* brow = W + (size_t)(col0 + srow) * EE + shalf * 16;
    const int sbase = srow * 40 + shalf * 16;

    {
        float4 fa[4], fb[4];
#pragma unroll
        for (int c = 0; c < 4; c++) {
            fa[c] = *(const float4*)(arow + c * 4);
            fb[c] = *(const float4*)(brow + c * 4);
        }
        unsigned short ua[16], ub[16];
#pragma unroll
        for (int c = 0; c < 4; c++) {
            ua[c*4+0] = f2bf(fa[c].x); ua[c*4+1] = f2bf(fa[c].y);
            ua[c*4+2] = f2bf(fa[c].z); ua[c*4+3] = f2bf(fa[c].w);
            ub[c*4+0] = f2bf(fb[c].x); ub[c*4+1] = f2bf(fb[c].y);
            ub[c*4+2] = f2bf(fb[c].z); ub[c*4+3] = f2bf(fb[c].w);
        }
        *(short8v*)&Asm[0][sbase + 0] = *(short8v*)&ua[0];
        *(short8v*)&Asm[0][sbase + 8] = *(short8v*)&ua[8];
        *(short8v*)&Bsm[0][sbase + 0] = *(short8v*)&ub[0];
        *(short8v*)&Bsm[0][sbase + 8] = *(short8v*)&ub[8];
    }
    __syncthreads();

    int cur = 0;
    for (int t = 0; t < EE / 32; t++) {
        float4 fa[4], fb[4];
        const bool more = (t + 1) < EE / 32;
        if (more) {
            const int k0 = (t + 1) * 32;
#pragma unroll
            for (int c = 0; c < 4; c++) {
                fa[c] = *(const float4*)(arow + k0 + c * 4);
                fb[c] = *(const float4*)(brow + k0 + c * 4);
            }
        }

        short8v afr[4], bfr[4];
#pragma unroll
        for (int mr = 0; mr < 4; mr++)
            afr[mr] = *(const short8v*)&Asm[cur][(wr*64 + mr*16 + lr16)*40 + kg*8];
#pragma unroll
        for (int nr = 0; nr < 4; nr++)
            bfr[nr] = *(const short8v*)&Bsm[cur][(wc*64 + nr*16 + lr16)*40 + kg*8];
#pragma unroll
        for (int mr = 0; mr < 4; mr++)
#pragma unroll
            for (int nr = 0; nr < 4; nr++)
                acc[mr][nr] = __builtin_amdgcn_mfma_f32_16x16x32_bf16(
                    afr[mr], bfr[nr], acc[mr][nr], 0, 0, 0);

        if (more) {
            const int nb = cur ^ 1;
            unsigned short ua[16], ub[16];
#pragma unroll
            for (int c = 0; c < 4; c++) {
                ua[c*4+0] = f2bf(fa[c].x); ua[c*4+1] = f2bf(fa[c].y);
                ua[c*4+2] = f2bf(fa[c].z); ua[c*4+3] = f2bf(fa[c].w);
                ub[c*4+0] = f2bf(fb[c].x); ub[c*4+1] = f2bf(fb[c].y);
                ub[c*4+2] = f2bf(fb[c].z); ub[c*4+3] = f2bf(fb[c].w);
            }
            *(short8v*)&Asm[nb][sbase + 0] = *(short8v*)&ua[0];
            *(short8v*)&Asm[nb][sbase + 8] = *(short8v*)&ua[8];
            *(short8v*)&Bsm[nb][sbase + 0] = *(short8v*)&ub[0];
            *(short8v*)&Bsm[nb][sbase + 8] = *(short8v*)&ub[8];
        }
        __syncthreads();
        cur ^= 1;
    }

#pragma unroll
    for (int mr = 0; mr < 4; mr++) {
#pragma unroll
        for (int nr = 0; nr < 4; nr++) {
            const int n = col0 + wc * 64 + nr * 16 + lr16;
            const float bv = bias[n];
#pragma unroll
            for (int j = 0; j < 4; j++) {
                const int m = row0 + wr * 64 + mr * 16 + kg * 4 + j;
                const float val = acc[mr][nr][j] + bv;
                if (mode == 0) {
                    dstf[(size_t)m * EE + n] = val;
                } else {
                    const int bi = m >> 11, l = m & (LL - 1);
                    const int hh = n >> 6, d = n & 63;
                    dstv[((size_t)(bi * HH + hh) * DHD + d) * LL + l] = f2bf(val);
                }
            }
        }
    }
}

// ---------------- MFMA windowed attention -----------------------------------
// 1024 blocks x 4 waves; wave w owns 16 rows r0w..r0w+15 over window
// [lo, lo+271] (17 B-frags). fp16-split QK (3 MFMA/frag/kfrag), f32 softmax
// in C-layout registers, P via per-wave LDS (bf16), PV bf16 MFMA with V^T
// global B-frags. Col 0 scalar side-path; row 0 fixed up by attn_row0.
__global__ __launch_bounds__(256) void attn_mfma(
    const unsigned short* __restrict__ qhi, const unsigned short* __restrict__ qlo,
    const unsigned short* __restrict__ khi, const unsigned short* __restrict__ klo,
    const unsigned short* __restrict__ vt, const float* __restrict__ pos_bias,
    float* __restrict__ attn_out)
{
    const int bid = blockIdx.x;
    const int head = bid & 31, chunk = bid >> 5;   // XCD-local: head%8 fixed
    const int b = head >> 4, h = head & 15;
    const int tid = threadIdx.x;
    const int w = tid >> 6, lane = tid & 63;
    const int lq = lane & 15, kg = lane >> 4;
    const int r0w = chunk * 64 + w * 16;

    __shared__ __align__(16) unsigned short Pl[4][16][296];
    __shared__ float s0s[4][16];

    const size_t bh = (size_t)(b * HH + h);
    const size_t bhL = bh * LL;
    const unsigned short* qhb = qhi + (bhL + r0w) * DHD;
    const unsigned short* qlb = qlo + (bhL + r0w) * DHD;
    const unsigned short* khb = khi + bhL * DHD;
    const unsigned short* klb = klo + bhL * DHD;
    const unsigned short* vtb = vt + bh * DHD * LL;

    int lo = r0w - WIN; if (lo < 0) lo = 0;
    int hi = r0w + 15 + WIN; if (hi > LL - 1) hi = LL - 1;
    const bool has0 = (lo > 0);

    // zero P pad cols [272,296)
    for (int idx = lane; idx < 96; idx += 64) {
        const int rr = idx / 6, cc = 272 + (idx % 6) * 4;
        *(unsigned long long*)&Pl[w][rr][cc] = 0ull;
    }

    // Q A-frags (row = lane&15, k = kg*8+j per 32-k frag)
    half8v qfh[2], qfl[2];
#pragma unroll
    for (int kf = 0; kf < 2; kf++) {
        const int off = lq * DHD + kf * 32 + kg * 8;
        qfh[kf] = *(const half8v*)(qhb + off);
        qfl[kf] = *(const half8v*)(qlb + off);
    }

    // ---- QK^T: 17 frags x 2 kfrags x 3 split terms ----
    f32x4 acc[17];
#pragma unroll
    for (int f = 0; f < 17; f++) {
        int c = lo + f * 16 + lq;
        const int cc = (c > LL - 1) ? (LL - 1) : c;
        const size_t kb = (size_t)cc * DHD;
        const half8v b0h = *(const half8v*)(khb + kb + kg * 8);
        const half8v b0l = *(const half8v*)(klb + kb + kg * 8);
        const half8v b1h = *(const half8v*)(khb + kb + 32 + kg * 8);
        const half8v b1l = *(const half8v*)(klb + kb + 32 + kg * 8);
        f32x4 a = (f32x4){0.f, 0.f, 0.f, 0.f};
        a = __builtin_amdgcn_mfma_f32_16x16x32_f16(qfl[0], b0h, a, 0, 0, 0);
        a = __builtin_amdgcn_mfma_f32_16x16x32_f16(qfh[0], b0l, a, 0, 0, 0);
        a = __builtin_amdgcn_mfma_f32_16x16x32_f16(qfh[0], b0h, a, 0, 0, 0);
        a = __builtin_amdgcn_mfma_f32_16x16x32_f16(qfl[1], b1h, a, 0, 0, 0);
        a = __builtin_amdgcn_mfma_f32_16x16x32_f16(qfh[1], b1l, a, 0, 0, 0);
        a = __builtin_amdgcn_mfma_f32_16x16x32_f16(qfh[1], b1h, a, 0, 0, 0);
        acc[f] = a;
    }

    // ---- col-0 scalar dot (A-layout: row = lane&15) ----
    float sc0 = -FLT_MAX;
    if (has0) {
        float part = 0.f;
        const int rowoff = lq * DHD;
#pragma unroll
        for (int e = 0; e < 16; e++) {
            const int d = kg * 16 + e;
            const float qv = h2f_u(qhb[rowoff + d]) + h2f_u(qlb[rowoff + d]);
            const float kv = h2f_u(khb[d]) + h2f_u(klb[d]);
            part = fmaf(qv, kv, part);
        }
        part += __shfl_xor(part, 16);
        part += __shfl_xor(part, 32);
        const float s = part * 0.125f;
        sc0 = (s > 0.f) ? s + pos_bias[(size_t)(r0w + lq) * LL] : -FLT_MAX;
    }
    if (lane < 16) s0s[w][lq] = sc0;

    // ---- gate + bias (C-layout: col = lane&15, row = kg*4+rg) ----
#pragma unroll
    for (int f = 0; f < 17; f++) {
        const int c = lo + f * 16 + lq;
        const bool cok = (c <= hi);
        f32x4 s4 = acc[f];
#pragma unroll
        for (int rg = 0; rg < 4; rg++) {
            const int r = r0w + kg * 4 + rg;
            const bool allowed = cok &&
                ((c == 0) || ((c >= r - WIN) && (c <= r + WIN)));
            const float s = s4[rg] * 0.125f;
            float sc = -FLT_MAX;
            if (allowed && s > 0.f) sc = s + pos_bias[(size_t)r * LL + c];
            s4[rg] = sc;
        }
        acc[f] = s4;
    }

    // ---- softmax (in-register, 16-lane butterflies) ----
    float s0r[4], mx[4];
#pragma unroll
    for (int rg = 0; rg < 4; rg++) {
        s0r[rg] = s0s[w][kg * 4 + rg];
        float m = s0r[rg];
#pragma unroll
        for (int f = 0; f < 17; f++) m = fmaxf(m, acc[f][rg]);
        m = fmaxf(m, __shfl_xor(m, 1));
        m = fmaxf(m, __shfl_xor(m, 2));
        m = fmaxf(m, __shfl_xor(m, 4));
        m = fmaxf(m, __shfl_xor(m, 8));
        mx[rg] = m;
    }

    float sum0 = 0.f, sum1 = 0.f, sum2 = 0.f, sum3 = 0.f;
#pragma unroll
    for (int f = 0; f < 17; f++) {
        const float p0_ = __expf(acc[f][0] - mx[0]); sum0 += p0_;
        const float p1_ = __expf(acc[f][1] - mx[1]); sum1 += p1_;
        const float p2_ = __expf(acc[f][2] - mx[2]); sum2 += p2_;
        const float p3_ = __expf(acc[f][3] - mx[3]); sum3 += p3_;
        Pl[w][kg * 4 + 0][f * 16 + lq] = f2bf(p0_);
        Pl[w][kg * 4 + 1][f * 16 + lq] = f2bf(p1_);
        Pl[w][kg * 4 + 2][f * 16 + lq] = f2bf(p2_);
        Pl[w][kg * 4 + 3][f * 16 + lq] = f2bf(p3_);
    }

    float inv[4], p0v[4];
    float sums[4] = {sum0, sum1, sum2, sum3};
#pragma unroll
    for (int rg = 0; rg < 4; rg++) {
        float s = sums[rg];
        s += __shfl_xor(s, 1);
        s += __shfl_xor(s, 2);
        s += __shfl_xor(s, 4);
        s += __shfl_xor(s, 8);
        const float p0 = has0 ? __expf(s0r[rg] - mx[rg]) : 0.f;
        p0v[rg] = p0;
        inv[rg] = 1.0f / (s + p0);
    }

    // ---- PV: A = P (LDS), B = V^T (global bf16) ----
    f32x4 pacc[4];
#pragma unroll
    for (int nf = 0; nf < 4; nf++) pacc[nf] = (f32x4){0.f, 0.f, 0.f, 0.f};
#pragma unroll
    for (int kf = 0; kf < 9; kf++) {
        const short8v pa = *(const short8v*)&Pl[w][lq][kf * 32 + kg * 8];
        int c0 = lo + kf * 32 + kg * 8;
        if (c0 > LL - 8) c0 = LL - 8;       // clamped spans have P==0
#pragma unroll
        for (int nf = 0; nf < 4; nf++) {
            const short8v vb =
                *(const short8v*)(vtb + (size_t)(nf * 16 + lq) * LL + c0);
            pacc[nf] = __builtin_amdgcn_mfma_f32_16x16x32_bf16(
                pa, vb, pacc[nf], 0, 0, 0);
        }
    }

    // ---- epilogue: add col-0 term, normalize, store ----
#pragma unroll
    for (int nf = 0; nf < 4; nf++) {
        const int n = nf * 16 + lq;
        const float v0 = has0 ? bf2f(vtb[(size_t)n * LL]) : 0.f;
#pragma unroll
        for (int rg = 0; rg < 4; rg++) {
            const int r = r0w + kg * 4 + rg;
            const float o = (pacc[nf][rg] + p0v[rg] * v0) * inv[rg];
            attn_out[((size_t)(b * LL + r)) * EE + h * DHD + n] = o;
        }
    }
}

// ---------------- dense row-0 fix-up (32 blocks) ----------------------------
__global__ __launch_bounds__(256) void attn_row0(
    const unsigned short* __restrict__ qhi, const unsigned short* __restrict__ qlo,
    const unsigned short* __restrict__ khi, const unsigned short* __restrict__ klo,
    const unsigned short* __restrict__ vt, const float* __restrict__ pos_bias,
    float* __restrict__ attn_out)
{
    const int head = blockIdx.x;
    const int b = head >> 4, h = head & 15;
    const int tid = threadIdx.x;
    __shared__ float sc[LL];
    __shared__ float red[256];
    __shared__ float qs[DHD];
    const size_t bh = (size_t)(b * HH + h);
    const size_t bhL = bh * LL;

    if (tid < DHD)
        qs[tid] = h2f_u(qhi[bhL * DHD + tid]) + h2f_u(qlo[bhL * DHD + tid]);
    __syncthreads();

    for (int j = tid; j < LL; j += 256) {
        const unsigned short* kh = khi + (bhL + j) * DHD;
        const unsigned short* kl = klo + (bhL + j) * DHD;
        float s = 0.f;
#pragma unroll
        for (int d = 0; d < DHD; d++)
            s = fmaf(qs[d], h2f_u(kh[d]) + h2f_u(kl[d]), s);
        s *= 0.125f;
        sc[j] = (s > 0.f) ? s + pos_bias[j] : -FLT_MAX;
    }
    __syncthreads();

    float m = -FLT_MAX;
    for (int j = tid; j < LL; j += 256) m = fmaxf(m, sc[j]);
    red[tid] = m;
    __syncthreads();
    for (int s = 128; s > 0; s >>= 1) {
        if (tid < s) red[tid] = fmaxf(red[tid], red[tid + s]);
        __syncthreads();
    }
    m = red[0];
    __syncthreads();

    float lsum = 0.f;
    for (int j = tid; j < LL; j += 256) {
        const float p = expf(sc[j] - m);
        sc[j] = p;
        lsum += p;
    }
    red[tid] = lsum;
    __syncthreads();
    for (int s = 128; s > 0; s >>= 1) {
        if (tid < s) red[tid] += red[tid + s];
        __syncthreads();
    }
    const float inv = 1.0f / red[0];
    __syncthreads();

    const int d = tid & 63, part = tid >> 6;
    float a = 0.f;
    const unsigned short* vcol = vt + (bh * DHD + d) * LL;
    for (int j = part; j < LL; j += 4) {
        const float p = sc[j];
        if (p != 0.f) a += p * bf2f(vcol[j]);
    }
    red[tid] = a;
    __syncthreads();
    if (tid < 64) {
        const float tot = (red[tid] + red[tid + 64]) +
                          (red[tid + 128] + red[tid + 192]);
        attn_out[(size_t)b * LL * EE + h * DHD + tid] = tot * inv;
    }
}

extern "C" void kernel_launch(void* const* d_in, const int* in_sizes, int n_in,
                              void* d_out, int out_size, void* d_ws, size_t ws_size,
                              hipStream_t stream) {
    const float* x        = (const float*)d_in[0];
    const float* pos_bias = (const float*)d_in[1];
    const float* Wq = (const float*)d_in[2];
    const float* bq = (const float*)d_in[3];
    const float* Wk = (const float*)d_in[4];
    const float* bk = (const float*)d_in[5];
    const float* Wv = (const float*)d_in[6];
    const float* bv = (const float*)d_in[7];
    const float* Wo = (const float*)d_in[8];
    const float* bo = (const float*)d_in[9];
    float* out = (float*)d_out;

    const size_t PL = (size_t)BB * HH * LL * DHD;      // 4,194,304 elems
    unsigned short* usw = (unsigned short*)d_ws;
    unsigned short* qhi = usw;
    unsigned short* qlo = usw + PL;
    unsigned short* khi = usw + 2 * PL;
    unsigned short* klo = usw + 3 * PL;
    unsigned short* vt  = usw + 4 * PL;                // bf16 V^T [bh][64][2048]
    float* attn = (float*)(usw + 6 * PL);              // f32 [B,L,E]

    dim3 blk(256);
    dim3 g1(EE / 128, (BB * LL) / 128);
    gemm_nt_f16x2<<<g1, blk, 0, stream>>>(x, Wq, bq, qhi, qlo);
    gemm_nt_f16x2<<<g1, blk, 0, stream>>>(x, Wk, bk, khi, klo);
    gemm_nt_bf16 <<<g1, blk, 0, stream>>>(x, Wv, bv, nullptr, vt, 1);

    attn_mfma<<<dim3(1024), 256, 0, stream>>>(qhi, qlo, khi, klo, vt,
                                              pos_bias, attn);
    attn_row0<<<dim3(BB * HH), 256, 0, stream>>>(qhi, qlo, khi, klo, vt,
                                                 pos_bias, attn);

    gemm_nt_bf16<<<g1, blk, 0, stream>>>(attn, Wo, bo, out, nullptr, 0);
}

// Round 10
// 335.372 us; speedup vs baseline: 5.9782x; 1.1017x over previous
//
#include <hip/hip_runtime.h>
#include <float.h>

#define BB 2
#define LL 2048
#define EE 1024
#define HH 16
#define DHD 64
#define WIN 128

typedef __attribute__((ext_vector_type(8))) short short8v;       // 8 u16
typedef __attribute__((ext_vector_type(8))) _Float16 half8v;     // 8 fp16
typedef __attribute__((ext_vector_type(4))) float f32x4;

static __device__ __forceinline__ unsigned short f2h(float f) {
    union { _Float16 h; unsigned short u; } x; x.h = (_Float16)f; return x.u;
}
static __device__ __forceinline__ float h2f_u(unsigned short u) {
    union { unsigned short u; _Float16 h; } x{u}; return (float)x.h;
}
static __device__ __forceinline__ void f2h_split(float f, unsigned short& hi,
                                                 unsigned short& lo) {
    _Float16 h = (_Float16)f;          // RNE
    _Float16 l = (_Float16)(f - (float)h);
    union { _Float16 h; unsigned short u; } uh, ul;
    uh.h = h; ul.h = l;
    hi = uh.u; lo = ul.u;
}

// ---------------- prep: split x, Wq, Wk into fp16 hi/lo planes -------------
__global__ __launch_bounds__(256) void prep_split(
    const float* __restrict__ x, const float* __restrict__ Wq,
    const float* __restrict__ Wk,
    unsigned short* __restrict__ xh, unsigned short* __restrict__ xl,
    unsigned short* __restrict__ wqh, unsigned short* __restrict__ wql,
    unsigned short* __restrict__ wkh, unsigned short* __restrict__ wkl)
{
    const size_t NX = (size_t)BB * LL * EE;        // 4M
    const size_t NW = (size_t)EE * EE;             // 1M
    const size_t total = NX + 2 * NW;
    const size_t stride = (size_t)gridDim.x * 256 * 4;
    for (size_t i = (size_t)(blockIdx.x * 256 + threadIdx.x) * 4;
         i < total; i += stride) {
        const float* src; unsigned short *dh, *dl; size_t off;
        if (i < NX)            { src = x;  dh = xh;  dl = xl;  off = i; }
        else if (i < NX + NW)  { src = Wq; dh = wqh; dl = wql; off = i - NX; }
        else                   { src = Wk; dh = wkh; dl = wkl; off = i - NX - NW; }
        const float4 v = *(const float4*)(src + off);
        ushort4 h4, l4;
        f2h_split(v.x, h4.x, l4.x);
        f2h_split(v.y, h4.y, l4.y);
        f2h_split(v.z, h4.z, l4.z);
        f2h_split(v.w, h4.w, l4.w);
        *(ushort4*)(dh + off) = h4;
        *(ushort4*)(dl + off) = l4;
    }
}

// ---------------- fused QKV projection GEMM --------------------------------
// grid (24, 32): bx>>3 = regime (0=Q split, 1=K split, 2=V fp16-hi).
// Pre-split operands: no conversion VALU in the Q/K K-loop. 128x128 tile,
// BK=32, single-buffered LDS (40 KB -> 3 blocks/CU), 4 waves x 64x64.
__global__ __launch_bounds__(256) void gemm_qkv(
    const unsigned short* __restrict__ xh, const unsigned short* __restrict__ xl,
    const unsigned short* __restrict__ wqh, const unsigned short* __restrict__ wql,
    const unsigned short* __restrict__ wkh, const unsigned short* __restrict__ wkl,
    const float* __restrict__ Wv,
    const float* __restrict__ bq, const float* __restrict__ bk,
    const float* __restrict__ bv,
    unsigned short* __restrict__ qhi, unsigned short* __restrict__ qlo,
    unsigned short* __restrict__ khi, unsigned short* __restrict__ klo,
    unsigned short* __restrict__ vt)
{
    __shared__ unsigned short Ah[128 * 40], Al[128 * 40];
    __shared__ unsigned short Bh[128 * 40], Bl[128 * 40];

    const int bx = blockIdx.x;
    const int regime = bx >> 3;              // 0=Q 1=K 2=V (block-uniform)
    const int col0 = (bx & 7) * 128;
    const int row0 = blockIdx.y * 128;
    const int tid = threadIdx.x;
    const int w = tid >> 6, lane = tid & 63;
    const int wr = w >> 1, wc = w & 1;
    const int lr16 = lane & 15, kg = lane >> 4;
    const int srow = tid >> 1, shalf = tid & 1;
    const int sbase = srow * 40 + shalf * 16;

    const unsigned short* bhsrc = (regime == 0) ? wqh : wkh;
    const unsigned short* blsrc = (regime == 0) ? wql : wkl;
    const float* bias = (regime == 0) ? bq : (regime == 1) ? bk : bv;

    const unsigned short* arow_h = xh + (size_t)(row0 + srow) * EE + shalf * 16;
    const unsigned short* arow_l = xl + (size_t)(row0 + srow) * EE + shalf * 16;
    const unsigned short* brow_h = bhsrc + (size_t)(col0 + srow) * EE + shalf * 16;
    const unsigned short* brow_l = blsrc + (size_t)(col0 + srow) * EE + shalf * 16;
    const float* vrow = Wv + (size_t)(col0 + srow) * EE + shalf * 16;

    f32x4 acc[4][4];
#pragma unroll
    for (int i = 0; i < 4; i++)
#pragma unroll
        for (int j = 0; j < 4; j++) acc[i][j] = (f32x4){0.f, 0.f, 0.f, 0.f};

    for (int t = 0; t < EE / 32; t++) {
        const int k0 = t * 32;
        short8v ra0, ra1, la0 = {}, la1 = {}, rb0, rb1, lb0 = {}, lb1 = {};
        ra0 = *(const short8v*)(arow_h + k0);
        ra1 = *(const short8v*)(arow_h + k0 + 8);
        if (regime < 2) {
            la0 = *(const short8v*)(arow_l + k0);
            la1 = *(const short8v*)(arow_l + k0 + 8);
            rb0 = *(const short8v*)(brow_h + k0);
            rb1 = *(const short8v*)(brow_h + k0 + 8);
            lb0 = *(const short8v*)(brow_l + k0);
            lb1 = *(const short8v*)(brow_l + k0 + 8);
        } else {
            const float4 f0 = *(const float4*)(vrow + k0);
            const float4 f1 = *(const float4*)(vrow + k0 + 4);
            const float4 f2 = *(const float4*)(vrow + k0 + 8);
            const float4 f3 = *(const float4*)(vrow + k0 + 12);
            unsigned short ub[16];
            ub[0] = f2h(f0.x); ub[1] = f2h(f0.y); ub[2] = f2h(f0.z); ub[3] = f2h(f0.w);
            ub[4] = f2h(f1.x); ub[5] = f2h(f1.y); ub[6] = f2h(f1.z); ub[7] = f2h(f1.w);
            ub[8] = f2h(f2.x); ub[9] = f2h(f2.y); ub[10] = f2h(f2.z); ub[11] = f2h(f2.w);
            ub[12] = f2h(f3.x); ub[13] = f2h(f3.y); ub[14] = f2h(f3.z); ub[15] = f2h(f3.w);
            rb0 = *(short8v*)&ub[0];
            rb1 = *(short8v*)&ub[8];
        }
        __syncthreads();                         // prev iter reads done
        *(short8v*)&Ah[sbase + 0] = ra0;
        *(short8v*)&Ah[sbase + 8] = ra1;
        *(short8v*)&Bh[sbase + 0] = rb0;
        *(short8v*)&Bh[sbase + 8] = rb1;
        if (regime < 2) {
            *(short8v*)&Al[sbase + 0] = la0;
            *(short8v*)&Al[sbase + 8] = la1;
            *(short8v*)&Bl[sbase + 0] = lb0;
            *(short8v*)&Bl[sbase + 8] = lb1;
        }
        __syncthreads();                         // writes visible

        half8v afh[4], afl[4], bfh[4], bfl[4];
#pragma unroll
        for (int mr = 0; mr < 4; mr++) {
            const int off = (wr * 64 + mr * 16 + lr16) * 40 + kg * 8;
            afh[mr] = *(const half8v*)&Ah[off];
            if (regime < 2) afl[mr] = *(const half8v*)&Al[off];
        }
#pragma unroll
        for (int nr = 0; nr < 4; nr++) {
            const int off = (wc * 64 + nr * 16 + lr16) * 40 + kg * 8;
            bfh[nr] = *(const half8v*)&Bh[off];
            if (regime < 2) bfl[nr] = *(const half8v*)&Bl[off];
        }
        if (regime < 2) {
#pragma unroll
            for (int mr = 0; mr < 4; mr++)
#pragma unroll
                for (int nr = 0; nr < 4; nr++) {
                    acc[mr][nr] = __builtin_amdgcn_mfma_f32_16x16x32_f16(
                        afl[mr], bfh[nr], acc[mr][nr], 0, 0, 0);
                    acc[mr][nr] = __builtin_amdgcn_mfma_f32_16x16x32_f16(
                        afh[mr], bfl[nr], acc[mr][nr], 0, 0, 0);
                    acc[mr][nr] = __builtin_amdgcn_mfma_f32_16x16x32_f16(
                        afh[mr], bfh[nr], acc[mr][nr], 0, 0, 0);
                }
        } else {
#pragma unroll
            for (int mr = 0; mr < 4; mr++)
#pragma unroll
                for (int nr = 0; nr < 4; nr++)
                    acc[mr][nr] = __builtin_amdgcn_mfma_f32_16x16x32_f16(
                        afh[mr], bfh[nr], acc[mr][nr], 0, 0, 0);
        }
    }

    // epilogue: C/D layout col = lane&15, row = (lane>>4)*4 + reg
#pragma unroll
    for (int mr = 0; mr < 4; mr++) {
#pragma unroll
        for (int nr = 0; nr < 4; nr++) {
            const int n = col0 + wc * 64 + nr * 16 + lr16;
            const float bb = bias[n];
#pragma unroll
            for (int j = 0; j < 4; j++) {
                const int m = row0 + wr * 64 + mr * 16 + kg * 4 + j;
                const float val = acc[mr][nr][j] + bb;
                const int bi = m >> 11, l = m & (LL - 1);
                const int hh = n >> 6, d = n & 63;
                if (regime == 2) {
                    vt[((size_t)(bi * HH + hh) * DHD + d) * LL + l] = f2h(val);
                } else {
                    unsigned short hu, lu;
                    f2h_split(val, hu, lu);
                    const size_t o = ((size_t)(bi * HH + hh) * LL + l) * DHD + d;
                    if (regime == 0) { qhi[o] = hu; qlo[o] = lu; }
                    else             { khi[o] = hu; klo[o] = lu; }
                }
            }
        }
    }
}

// ---------------- MFMA windowed attention + fused row-0 --------------------
// blocks [0,1024): windowed path (skips r==0 store); blocks [1024,1056):
// dense row-0 path for head = bid-1024. Output: fp16 attn (u16).
__global__ __launch_bounds__(256) void attn_mfma(
    const unsigned short* __restrict__ qhi, const unsigned short* __restrict__ qlo,
    const unsigned short* __restrict__ khi, const unsigned short* __restrict__ klo,
    const unsigned short* __restrict__ vt, const float* __restrict__ pos_bias,
    unsigned short* __restrict__ attn16)
{
    __shared__ __align__(16) unsigned short Pl[4][16][296];
    __shared__ float s0s[4][16];

    const int bid = blockIdx.x;
    const int tid = threadIdx.x;

    if (bid >= 1024) {
        // ---- dense row 0 for one head ----
        const int head = bid - 1024;
        const int b = head >> 4, h = head & 15;
        float* sc = (float*)&Pl[0][0][0];
        float* red = sc + LL;
        float* qs = red + 256;
        const size_t bh = (size_t)(b * HH + h);
        const size_t bhL = bh * LL;

        if (tid < DHD)
            qs[tid] = h2f_u(qhi[bhL * DHD + tid]) + h2f_u(qlo[bhL * DHD + tid]);
        __syncthreads();

        for (int j = tid; j < LL; j += 256) {
            const unsigned short* kh = khi + (bhL + j) * DHD;
            const unsigned short* kl = klo + (bhL + j) * DHD;
            float s = 0.f;
#pragma unroll
            for (int d = 0; d < DHD; d++)
                s = fmaf(qs[d], h2f_u(kh[d]) + h2f_u(kl[d]), s);
            s *= 0.125f;
            sc[j] = (s > 0.f) ? s + pos_bias[j] : -FLT_MAX;
        }
        __syncthreads();

        float m = -FLT_MAX;
        for (int j = tid; j < LL; j += 256) m = fmaxf(m, sc[j]);
        red[tid] = m;
        __syncthreads();
        for (int s = 128; s > 0; s >>= 1) {
            if (tid < s) red[tid] = fmaxf(red[tid], red[tid + s]);
            __syncthreads();
        }
        m = red[0];
        __syncthreads();

        float lsum = 0.f;
        for (int j = tid; j < LL; j += 256) {
            const float p = expf(sc[j] - m);
            sc[j] = p;
            lsum += p;
        }
        red[tid] = lsum;
        __syncthreads();
        for (int s = 128; s > 0; s >>= 1) {
            if (tid < s) red[tid] += red[tid + s];
            __syncthreads();
        }
        const float inv = 1.0f / red[0];
        __syncthreads();

        const int d = tid & 63, part = tid >> 6;
        float a = 0.f;
        const unsigned short* vcol = vt + (bh * DHD + d) * LL;
        for (int j = part; j < LL; j += 4) {
            const float p = sc[j];
            if (p != 0.f) a += p * h2f_u(vcol[j]);
        }
        red[tid] = a;
        __syncthreads();
        if (tid < 64) {
            const float tot = (red[tid] + red[tid + 64]) +
                              (red[tid + 128] + red[tid + 192]);
            attn16[(size_t)b * LL * EE + h * DHD + tid] = f2h(tot * inv);
        }
        return;
    }

    // ---- windowed path ----
    const int head = bid & 31, chunk = bid >> 5;   // XCD-local: head%8 fixed
    const int b = head >> 4, h = head & 15;
    const int w = tid >> 6, lane = tid & 63;
    const int lq = lane & 15, kg = lane >> 4;
    const int r0w = chunk * 64 + w * 16;

    const size_t bh = (size_t)(b * HH + h);
    const size_t bhL = bh * LL;
    const unsigned short* qhb = qhi + (bhL + r0w) * DHD;
    const unsigned short* qlb = qlo + (bhL + r0w) * DHD;
    const unsigned short* khb = khi + bhL * DHD;
    const unsigned short* klb = klo + bhL * DHD;
    const unsigned short* vtb = vt + bh * DHD * LL;

    int lo = r0w - WIN; if (lo < 0) lo = 0;
    int hi = r0w + 15 + WIN; if (hi > LL - 1) hi = LL - 1;
    const bool has0 = (lo > 0);

    // zero P pad cols [272,296)
    for (int idx = lane; idx < 96; idx += 64) {
        const int rr = idx / 6, cc = 272 + (idx % 6) * 4;
        *(unsigned long long*)&Pl[w][rr][cc] = 0ull;
    }

    half8v qfh[2], qfl[2];
#pragma unroll
    for (int kf = 0; kf < 2; kf++) {
        const int off = lq * DHD + kf * 32 + kg * 8;
        qfh[kf] = *(const half8v*)(qhb + off);
        qfl[kf] = *(const half8v*)(qlb + off);
    }

    // ---- QK^T: 17 frags x 2 kfrags x 3 split terms ----
    f32x4 acc[17];
#pragma unroll
    for (int f = 0; f < 17; f++) {
        int c = lo + f * 16 + lq;
        const int cc = (c > LL - 1) ? (LL - 1) : c;
        const size_t kb = (size_t)cc * DHD;
        const half8v b0h = *(const half8v*)(khb + kb + kg * 8);
        const half8v b0l = *(const half8v*)(klb + kb + kg * 8);
        const half8v b1h = *(const half8v*)(khb + kb + 32 + kg * 8);
        const half8v b1l = *(const half8v*)(klb + kb + 32 + kg * 8);
        f32x4 a = (f32x4){0.f, 0.f, 0.f, 0.f};
        a = __builtin_amdgcn_mfma_f32_16x16x32_f16(qfl[0], b0h, a, 0, 0, 0);
        a = __builtin_amdgcn_mfma_f32_16x16x32_f16(qfh[0], b0l, a, 0, 0, 0);
        a = __builtin_amdgcn_mfma_f32_16x16x32_f16(qfh[0], b0h, a, 0, 0, 0);
        a = __builtin_amdgcn_mfma_f32_16x16x32_f16(qfl[1], b1h, a, 0, 0, 0);
        a = __builtin_amdgcn_mfma_f32_16x16x32_f16(qfh[1], b1l, a, 0, 0, 0);
        a = __builtin_amdgcn_mfma_f32_16x16x32_f16(qfh[1], b1h, a, 0, 0, 0);
        acc[f] = a;
    }

    // ---- col-0 scalar dot ----
    float sc0 = -FLT_MAX;
    if (has0) {
        float part = 0.f;
        const int rowoff = lq * DHD;
#pragma unroll
        for (int e = 0; e < 16; e++) {
            const int d = kg * 16 + e;
            const float qv = h2f_u(qhb[rowoff + d]) + h2f_u(qlb[rowoff + d]);
            const float kv = h2f_u(khb[d]) + h2f_u(klb[d]);
            part = fmaf(qv, kv, part);
        }
        part += __shfl_xor(part, 16);
        part += __shfl_xor(part, 32);
        const float s = part * 0.125f;
        sc0 = (s > 0.f) ? s + pos_bias[(size_t)(r0w + lq) * LL] : -FLT_MAX;
    }
    if (lane < 16) s0s[w][lq] = sc0;

    // ---- gate + bias (C-layout: col = lane&15, row = kg*4+rg) ----
#pragma unroll
    for (int f = 0; f < 17; f++) {
        const int c = lo + f * 16 + lq;
        const bool cok = (c <= hi);
        f32x4 s4 = acc[f];
#pragma unroll
        for (int rg = 0; rg < 4; rg++) {
            const int r = r0w + kg * 4 + rg;
            const bool allowed = cok &&
                ((c == 0) || ((c >= r - WIN) && (c <= r + WIN)));
            const float s = s4[rg] * 0.125f;
            float sc = -FLT_MAX;
            if (allowed && s > 0.f) sc = s + pos_bias[(size_t)r * LL + c];
            s4[rg] = sc;
        }
        acc[f] = s4;
    }

    // ---- softmax (in-register, 16-lane butterflies) ----
    float s0r[4], mx[4];
#pragma unroll
    for (int rg = 0; rg < 4; rg++) {
        s0r[rg] = s0s[w][kg * 4 + rg];
        float m = s0r[rg];
#pragma unroll
        for (int f = 0; f < 17; f++) m = fmaxf(m, acc[f][rg]);
        m = fmaxf(m, __shfl_xor(m, 1));
        m = fmaxf(m, __shfl_xor(m, 2));
        m = fmaxf(m, __shfl_xor(m, 4));
        m = fmaxf(m, __shfl_xor(m, 8));
        mx[rg] = m;
    }

    float sum0 = 0.f, sum1 = 0.f, sum2 = 0.f, sum3 = 0.f;
#pragma unroll
    for (int f = 0; f < 17; f++) {
        const float p0_ = __expf(acc[f][0] - mx[0]); sum0 += p0_;
        const float p1_ = __expf(acc[f][1] - mx[1]); sum1 += p1_;
        const float p2_ = __expf(acc[f][2] - mx[2]); sum2 += p2_;
        const float p3_ = __expf(acc[f][3] - mx[3]); sum3 += p3_;
        Pl[w][kg * 4 + 0][f * 16 + lq] = f2h(p0_);
        Pl[w][kg * 4 + 1][f * 16 + lq] = f2h(p1_);
        Pl[w][kg * 4 + 2][f * 16 + lq] = f2h(p2_);
        Pl[w][kg * 4 + 3][f * 16 + lq] = f2h(p3_);
    }

    float inv[4], p0v[4];
    float sums[4] = {sum0, sum1, sum2, sum3};
#pragma unroll
    for (int rg = 0; rg < 4; rg++) {
        float s = sums[rg];
        s += __shfl_xor(s, 1);
        s += __shfl_xor(s, 2);
        s += __shfl_xor(s, 4);
        s += __shfl_xor(s, 8);
        const float p0 = has0 ? __expf(s0r[rg] - mx[rg]) : 0.f;
        p0v[rg] = p0;
        inv[rg] = 1.0f / (s + p0);
    }

    // ---- PV: A = P (LDS fp16), B = V^T (global fp16) ----
    f32x4 pacc[4];
#pragma unroll
    for (int nf = 0; nf < 4; nf++) pacc[nf] = (f32x4){0.f, 0.f, 0.f, 0.f};
#pragma unroll
    for (int kf = 0; kf < 9; kf++) {
        const half8v pa = *(const half8v*)&Pl[w][lq][kf * 32 + kg * 8];
        int c0 = lo + kf * 32 + kg * 8;
        if (c0 > LL - 8) c0 = LL - 8;       // clamped spans have P==0
#pragma unroll
        for (int nf = 0; nf < 4; nf++) {
            const half8v vb =
                *(const half8v*)(vtb + (size_t)(nf * 16 + lq) * LL + c0);
            pacc[nf] = __builtin_amdgcn_mfma_f32_16x16x32_f16(
                pa, vb, pacc[nf], 0, 0, 0);
        }
    }

    // ---- epilogue ----
#pragma unroll
    for (int nf = 0; nf < 4; nf++) {
        const int n = nf * 16 + lq;
        const float v0 = has0 ? h2f_u(vtb[(size_t)n * LL]) : 0.f;
#pragma unroll
        for (int rg = 0; rg < 4; rg++) {
            const int r = r0w + kg * 4 + rg;
            const float o = (pacc[nf][rg] + p0v[rg] * v0) * inv[rg];
            if (r != 0)
                attn16[((size_t)(b * LL + r)) * EE + h * DHD + n] = f2h(o);
        }
    }
}

// ---------------- out-proj: fp16 x fp16 MFMA, f32 out ----------------------
__global__ __launch_bounds__(256) void gemm_o(
    const unsigned short* __restrict__ attn16, const float* __restrict__ Wo,
    const float* __restrict__ bo, float* __restrict__ out)
{
    __shared__ unsigned short Ah[128 * 40], Bh[128 * 40];

    const int tid = threadIdx.x;
    const int w = tid >> 6, lane = tid & 63;
    const int wr = w >> 1, wc = w & 1;
    const int lr16 = lane & 15, kg = lane >> 4;
    const int row0 = blockIdx.y * 128, col0 = blockIdx.x * 128;
    const int srow = tid >> 1, shalf = tid & 1;
    const int sbase = srow * 40 + shalf * 16;

    const unsigned short* arow = attn16 + (size_t)(row0 + srow) * EE + shalf * 16;
    const float* brow = Wo + (size_t)(col0 + srow) * EE + shalf * 16;

    f32x4 acc[4][4];
#pragma unroll
    for (int i = 0; i < 4; i++)
#pragma unroll
        for (int j = 0; j < 4; j++) acc[i][j] = (f32x4){0.f, 0.f, 0.f, 0.f};

    for (int t = 0; t < EE / 32; t++) {
        const int k0 = t * 32;
        const short8v ra0 = *(const short8v*)(arow + k0);
        const short8v ra1 = *(const short8v*)(arow + k0 + 8);
        const float4 f0 = *(const float4*)(brow + k0);
        const float4 f1 = *(const float4*)(brow + k0 + 4);
        const float4 f2 = *(const float4*)(brow + k0 + 8);
        const float4 f3 = *(const float4*)(brow + k0 + 12);
        unsigned short ub[16];
        ub[0] = f2h(f0.x); ub[1] = f2h(f0.y); ub[2] = f2h(f0.z); ub[3] = f2h(f0.w);
        ub[4] = f2h(f1.x); ub[5] = f2h(f1.y); ub[6] = f2h(f1.z); ub[7] = f2h(f1.w);
        ub[8] = f2h(f2.x); ub[9] = f2h(f2.y); ub[10] = f2h(f2.z); ub[11] = f2h(f2.w);
        ub[12] = f2h(f3.x); ub[13] = f2h(f3.y); ub[14] = f2h(f3.z); ub[15] = f2h(f3.w);
        __syncthreads();
        *(short8v*)&Ah[sbase + 0] = ra0;
        *(short8v*)&Ah[sbase + 8] = ra1;
        *(short8v*)&Bh[sbase + 0] = *(short8v*)&ub[0];
        *(short8v*)&Bh[sbase + 8] = *(short8v*)&ub[8];
        __syncthreads();

        half8v af[4], bf[4];
#pragma unroll
        for (int mr = 0; mr < 4; mr++)
            af[mr] = *(const half8v*)&Ah[(wr*64 + mr*16 + lr16)*40 + kg*8];
#pragma unroll
        for (int nr = 0; nr < 4; nr++)
            bf[nr] = *(const half8v*)&Bh[(wc*64 + nr*16 + lr16)*40 + kg*8];
#pragma unroll
        for (int mr = 0; mr < 4; mr++)
#pragma unroll
            for (int nr = 0; nr < 4; nr++)
                acc[mr][nr] = __builtin_amdgcn_mfma_f32_16x16x32_f16(
                    af[mr], bf[nr], acc[mr][nr], 0, 0, 0);
    }

#pragma unroll
    for (int mr = 0; mr < 4; mr++) {
#pragma unroll
        for (int nr = 0; nr < 4; nr++) {
            const int n = col0 + wc * 64 + nr * 16 + lr16;
            const float bb = bo[n];
#pragma unroll
            for (int j = 0; j < 4; j++) {
                const int m = row0 + wr * 64 + mr * 16 + kg * 4 + j;
                out[(size_t)m * EE + n] = acc[mr][nr][j] + bb;
            }
        }
    }
}

extern "C" void kernel_launch(void* const* d_in, const int* in_sizes, int n_in,
                              void* d_out, int out_size, void* d_ws, size_t ws_size,
                              hipStream_t stream) {
    const float* x        = (const float*)d_in[0];
    const float* pos_bias = (const float*)d_in[1];
    const float* Wq = (const float*)d_in[2];
    const float* bq = (const float*)d_in[3];
    const float* Wk = (const float*)d_in[4];
    const float* bk = (const float*)d_in[5];
    const float* Wv = (const float*)d_in[6];
    const float* bv = (const float*)d_in[7];
    const float* Wo = (const float*)d_in[8];
    const float* bo = (const float*)d_in[9];
    float* out = (float*)d_out;

    const size_t M1 = (size_t)1024 * 1024;         // 1M u16 units
    unsigned short* u = (unsigned short*)d_ws;
    unsigned short* xh  = u;                        // 4M
    unsigned short* xl  = u + 4 * M1;               // 4M
    unsigned short* wqh = u + 8 * M1;               // 1M each
    unsigned short* wql = u + 9 * M1;
    unsigned short* wkh = u + 10 * M1;
    unsigned short* wkl = u + 11 * M1;
    unsigned short* qhi = u + 12 * M1;              // 4M each
    unsigned short* qlo = u + 16 * M1;
    unsigned short* khi = u + 20 * M1;
    unsigned short* klo = u + 24 * M1;
    unsigned short* vt  = u + 28 * M1;              // 4M -> 32M u16 = 64 MB
    unsigned short* attn16 = xh;                    // reuse (xh dead post-QKV)

    prep_split<<<dim3(2048), 256, 0, stream>>>(x, Wq, Wk, xh, xl,
                                               wqh, wql, wkh, wkl);
    gemm_qkv<<<dim3(24, 32), 256, 0, stream>>>(xh, xl, wqh, wql, wkh, wkl,
                                               Wv, bq, bk, bv,
                                               qhi, qlo, khi, klo, vt);
    attn_mfma<<<dim3(1056), 256, 0, stream>>>(qhi, qlo, khi, klo, vt,
                                              pos_bias, attn16);
    gemm_o<<<dim3(8, 32), 256, 0, stream>>>(attn16, Wo, bo, out);
}

// Round 11
// 276.618 us; speedup vs baseline: 7.2480x; 1.2124x over previous
//
#include <hip/hip_runtime.h>
#include <float.h>

#define BB 2
#define LL 2048
#define EE 1024
#define HH 16
#define DHD 64
#define WIN 128

typedef __attribute__((ext_vector_type(8))) short short8v;       // 8 u16
typedef __attribute__((ext_vector_type(8))) _Float16 half8v;     // 8 fp16
typedef __attribute__((ext_vector_type(4))) float f32x4;

static __device__ __forceinline__ unsigned short f2h(float f) {
    union { _Float16 h; unsigned short u; } x; x.h = (_Float16)f; return x.u;
}
static __device__ __forceinline__ float h2f_u(unsigned short u) {
    union { unsigned short u; _Float16 h; } x{u}; return (float)x.h;
}
static __device__ __forceinline__ void f2h_split(float f, unsigned short& hi,
                                                 unsigned short& lo) {
    _Float16 h = (_Float16)f;          // RNE
    _Float16 l = (_Float16)(f - (float)h);
    union { _Float16 h; unsigned short u; } uh, ul;
    uh.h = h; ul.h = l;
    hi = uh.u; lo = ul.u;
}

// ---------------- prep: split x, Wq, Wk into fp16 hi/lo planes -------------
__global__ __launch_bounds__(256) void prep_split(
    const float* __restrict__ x, const float* __restrict__ Wq,
    const float* __restrict__ Wk,
    unsigned short* __restrict__ xh, unsigned short* __restrict__ xl,
    unsigned short* __restrict__ wqh, unsigned short* __restrict__ wql,
    unsigned short* __restrict__ wkh, unsigned short* __restrict__ wkl)
{
    const size_t NX = (size_t)BB * LL * EE;        // 4M
    const size_t NW = (size_t)EE * EE;             // 1M
    const size_t total = NX + 2 * NW;
    const size_t stride = (size_t)gridDim.x * 256 * 4;
    for (size_t i = (size_t)(blockIdx.x * 256 + threadIdx.x) * 4;
         i < total; i += stride) {
        const float* src; unsigned short *dh, *dl; size_t off;
        if (i < NX)            { src = x;  dh = xh;  dl = xl;  off = i; }
        else if (i < NX + NW)  { src = Wq; dh = wqh; dl = wql; off = i - NX; }
        else                   { src = Wk; dh = wkh; dl = wkl; off = i - NX - NW; }
        const float4 v = *(const float4*)(src + off);
        ushort4 h4, l4;
        f2h_split(v.x, h4.x, l4.x);
        f2h_split(v.y, h4.y, l4.y);
        f2h_split(v.z, h4.z, l4.z);
        f2h_split(v.w, h4.w, l4.w);
        *(ushort4*)(dh + off) = h4;
        *(ushort4*)(dl + off) = l4;
    }
}

// ---------------- pack pos_bias into windowed layout -----------------------
// pbp[r][t] = pos_bias[r][lo_w(r) + t], lo_w(r) = max(0, (r&~15) - WIN),
// t in [0,272); pb0[r] = pos_bias[r][0]. 2.2 MB -> L2-resident, coalesced.
__global__ __launch_bounds__(256) void pack_bias(
    const float* __restrict__ pb, float* __restrict__ pbp,
    float* __restrict__ pb0)
{
    const int r = blockIdx.x;
    int lo_w = (r & ~15) - WIN; if (lo_w < 0) lo_w = 0;
    for (int t = threadIdx.x; t < 272; t += 256) {
        const int c = lo_w + t;
        pbp[(size_t)r * 272 + t] = (c < LL) ? pb[(size_t)r * LL + c] : 0.f;
    }
    if (threadIdx.x == 0) pb0[r] = pb[(size_t)r * LL];
}

// ---------------- fused QKV projection GEMM --------------------------------
// grid (24, 32): bx>>3 = regime (0=Q split, 1=K split, 2=V fp16-hi).
__global__ __launch_bounds__(256) void gemm_qkv(
    const unsigned short* __restrict__ xh, const unsigned short* __restrict__ xl,
    const unsigned short* __restrict__ wqh, const unsigned short* __restrict__ wql,
    const unsigned short* __restrict__ wkh, const unsigned short* __restrict__ wkl,
    const float* __restrict__ Wv,
    const float* __restrict__ bq, const float* __restrict__ bk,
    const float* __restrict__ bv,
    unsigned short* __restrict__ qhi, unsigned short* __restrict__ qlo,
    unsigned short* __restrict__ khi, unsigned short* __restrict__ klo,
    unsigned short* __restrict__ vt)
{
    __shared__ unsigned short Ah[128 * 40], Al[128 * 40];
    __shared__ unsigned short Bh[128 * 40], Bl[128 * 40];

    const int bx = blockIdx.x;
    const int regime = bx >> 3;              // 0=Q 1=K 2=V (block-uniform)
    const int col0 = (bx & 7) * 128;
    const int row0 = blockIdx.y * 128;
    const int tid = threadIdx.x;
    const int w = tid >> 6, lane = tid & 63;
    const int wr = w >> 1, wc = w & 1;
    const int lr16 = lane & 15, kg = lane >> 4;
    const int srow = tid >> 1, shalf = tid & 1;
    const int sbase = srow * 40 + shalf * 16;

    const unsigned short* bhsrc = (regime == 0) ? wqh : wkh;
    const unsigned short* blsrc = (regime == 0) ? wql : wkl;
    const float* bias = (regime == 0) ? bq : (regime == 1) ? bk : bv;

    const unsigned short* arow_h = xh + (size_t)(row0 + srow) * EE + shalf * 16;
    const unsigned short* arow_l = xl + (size_t)(row0 + srow) * EE + shalf * 16;
    const unsigned short* brow_h = bhsrc + (size_t)(col0 + srow) * EE + shalf * 16;
    const unsigned short* brow_l = blsrc + (size_t)(col0 + srow) * EE + shalf * 16;
    const float* vrow = Wv + (size_t)(col0 + srow) * EE + shalf * 16;

    f32x4 acc[4][4];
#pragma unroll
    for (int i = 0; i < 4; i++)
#pragma unroll
        for (int j = 0; j < 4; j++) acc[i][j] = (f32x4){0.f, 0.f, 0.f, 0.f};

    for (int t = 0; t < EE / 32; t++) {
        const int k0 = t * 32;
        short8v ra0, ra1, la0 = {}, la1 = {}, rb0, rb1, lb0 = {}, lb1 = {};
        ra0 = *(const short8v*)(arow_h + k0);
        ra1 = *(const short8v*)(arow_h + k0 + 8);
        if (regime < 2) {
            la0 = *(const short8v*)(arow_l + k0);
            la1 = *(const short8v*)(arow_l + k0 + 8);
            rb0 = *(const short8v*)(brow_h + k0);
            rb1 = *(const short8v*)(brow_h + k0 + 8);
            lb0 = *(const short8v*)(brow_l + k0);
            lb1 = *(const short8v*)(brow_l + k0 + 8);
        } else {
            const float4 f0 = *(const float4*)(vrow + k0);
            const float4 f1 = *(const float4*)(vrow + k0 + 4);
            const float4 f2 = *(const float4*)(vrow + k0 + 8);
            const float4 f3 = *(const float4*)(vrow + k0 + 12);
            unsigned short ub[16];
            ub[0] = f2h(f0.x); ub[1] = f2h(f0.y); ub[2] = f2h(f0.z); ub[3] = f2h(f0.w);
            ub[4] = f2h(f1.x); ub[5] = f2h(f1.y); ub[6] = f2h(f1.z); ub[7] = f2h(f1.w);
            ub[8] = f2h(f2.x); ub[9] = f2h(f2.y); ub[10] = f2h(f2.z); ub[11] = f2h(f2.w);
            ub[12] = f2h(f3.x); ub[13] = f2h(f3.y); ub[14] = f2h(f3.z); ub[15] = f2h(f3.w);
            rb0 = *(short8v*)&ub[0];
            rb1 = *(short8v*)&ub[8];
        }
        __syncthreads();                         // prev iter reads done
        *(short8v*)&Ah[sbase + 0] = ra0;
        *(short8v*)&Ah[sbase + 8] = ra1;
        *(short8v*)&Bh[sbase + 0] = rb0;
        *(short8v*)&Bh[sbase + 8] = rb1;
        if (regime < 2) {
            *(short8v*)&Al[sbase + 0] = la0;
            *(short8v*)&Al[sbase + 8] = la1;
            *(short8v*)&Bl[sbase + 0] = lb0;
            *(short8v*)&Bl[sbase + 8] = lb1;
        }
        __syncthreads();                         // writes visible

        half8v afh[4], afl[4], bfh[4], bfl[4];
#pragma unroll
        for (int mr = 0; mr < 4; mr++) {
            const int off = (wr * 64 + mr * 16 + lr16) * 40 + kg * 8;
            afh[mr] = *(const half8v*)&Ah[off];
            if (regime < 2) afl[mr] = *(const half8v*)&Al[off];
        }
#pragma unroll
        for (int nr = 0; nr < 4; nr++) {
            const int off = (wc * 64 + nr * 16 + lr16) * 40 + kg * 8;
            bfh[nr] = *(const half8v*)&Bh[off];
            if (regime < 2) bfl[nr] = *(const half8v*)&Bl[off];
        }
        if (regime < 2) {
#pragma unroll
            for (int mr = 0; mr < 4; mr++)
#pragma unroll
                for (int nr = 0; nr < 4; nr++) {
                    acc[mr][nr] = __builtin_amdgcn_mfma_f32_16x16x32_f16(
                        afl[mr], bfh[nr], acc[mr][nr], 0, 0, 0);
                    acc[mr][nr] = __builtin_amdgcn_mfma_f32_16x16x32_f16(
                        afh[mr], bfl[nr], acc[mr][nr], 0, 0, 0);
                    acc[mr][nr] = __builtin_amdgcn_mfma_f32_16x16x32_f16(
                        afh[mr], bfh[nr], acc[mr][nr], 0, 0, 0);
                }
        } else {
#pragma unroll
            for (int mr = 0; mr < 4; mr++)
#pragma unroll
                for (int nr = 0; nr < 4; nr++)
                    acc[mr][nr] = __builtin_amdgcn_mfma_f32_16x16x32_f16(
                        afh[mr], bfh[nr], acc[mr][nr], 0, 0, 0);
        }
    }

    // epilogue: C/D layout col = lane&15, row = (lane>>4)*4 + reg
#pragma unroll
    for (int mr = 0; mr < 4; mr++) {
#pragma unroll
        for (int nr = 0; nr < 4; nr++) {
            const int n = col0 + wc * 64 + nr * 16 + lr16;
            const float bb = bias[n];
#pragma unroll
            for (int j = 0; j < 4; j++) {
                const int m = row0 + wr * 64 + mr * 16 + kg * 4 + j;
                const float val = acc[mr][nr][j] + bb;
                const int bi = m >> 11, l = m & (LL - 1);
                const int hh = n >> 6, d = n & 63;
                if (regime == 2) {
                    vt[((size_t)(bi * HH + hh) * DHD + d) * LL + l] = f2h(val);
                } else {
                    unsigned short hu, lu;
                    f2h_split(val, hu, lu);
                    const size_t o = ((size_t)(bi * HH + hh) * LL + l) * DHD + d;
                    if (regime == 0) { qhi[o] = hu; qlo[o] = lu; }
                    else             { khi[o] = hu; klo[o] = lu; }
                }
            }
        }
    }
}

// ---------------- MFMA windowed attention + fused row-0 --------------------
// blocks [0,32): dense row-0 path, FIRST so they overlap the windowed phase
// (r10 put them last -> 70us serialized tail). blocks [32,1056): windowed.
__global__ __launch_bounds__(256) void attn_mfma(
    const unsigned short* __restrict__ qhi, const unsigned short* __restrict__ qlo,
    const unsigned short* __restrict__ khi, const unsigned short* __restrict__ klo,
    const unsigned short* __restrict__ vt, const float* __restrict__ pos_bias,
    const float* __restrict__ pbp, const float* __restrict__ pb0,
    unsigned short* __restrict__ attn16)
{
    __shared__ __align__(16) unsigned short Pl[4][16][296];
    __shared__ float s0s[4][16];

    const int bid = blockIdx.x;
    const int tid = threadIdx.x;

    if (bid < 32) {
        // ---- dense row 0 for one head (vectorized) ----
        const int head = bid;
        const int b = head >> 4, h = head & 15;
        float* sc = (float*)&Pl[0][0][0];
        float* red = sc + LL;
        float* qs = red + 256;
        const size_t bh = (size_t)(b * HH + h);
        const size_t bhL = bh * LL;

        if (tid < DHD)
            qs[tid] = h2f_u(qhi[bhL * DHD + tid]) + h2f_u(qlo[bhL * DHD + tid]);
        __syncthreads();

        for (int j = tid; j < LL; j += 256) {
            const unsigned short* kh = khi + (bhL + j) * DHD;
            const unsigned short* kl = klo + (bhL + j) * DHD;
            float s = 0.f;
#pragma unroll
            for (int d8 = 0; d8 < 8; d8++) {
                const half8v kh8 = *(const half8v*)(kh + d8 * 8);
                const half8v kl8 = *(const half8v*)(kl + d8 * 8);
#pragma unroll
                for (int e = 0; e < 8; e++)
                    s = fmaf(qs[d8 * 8 + e], (float)kh8[e] + (float)kl8[e], s);
            }
            s *= 0.125f;
            sc[j] = (s > 0.f) ? s + pos_bias[j] : -FLT_MAX;
        }
        __syncthreads();

        float m = -FLT_MAX;
        for (int j = tid; j < LL; j += 256) m = fmaxf(m, sc[j]);
        red[tid] = m;
        __syncthreads();
        for (int s = 128; s > 0; s >>= 1) {
            if (tid < s) red[tid] = fmaxf(red[tid], red[tid + s]);
            __syncthreads();
        }
        m = red[0];
        __syncthreads();

        float lsum = 0.f;
        for (int j = tid; j < LL; j += 256) {
            const float p = expf(sc[j] - m);
            sc[j] = p;
            lsum += p;
        }
        red[tid] = lsum;
        __syncthreads();
        for (int s = 128; s > 0; s >>= 1) {
            if (tid < s) red[tid] += red[tid + s];
            __syncthreads();
        }
        const float inv = 1.0f / red[0];
        __syncthreads();

        const int d = tid & 63, part = tid >> 6;
        float a = 0.f;
        const unsigned short* vcol = vt + (bh * DHD + d) * LL;
        for (int j0 = part * 8; j0 < LL; j0 += 32) {
            const half8v v8 = *(const half8v*)(vcol + j0);
#pragma unroll
            for (int e = 0; e < 8; e++)
                a = fmaf(sc[j0 + e], (float)v8[e], a);
        }
        red[tid] = a;
        __syncthreads();
        if (tid < 64) {
            const float tot = (red[tid] + red[tid + 64]) +
                              (red[tid + 128] + red[tid + 192]);
            attn16[(size_t)b * LL * EE + h * DHD + tid] = f2h(tot * inv);
        }
        return;
    }

    // ---- windowed path ----
    const int vbid = bid - 32;
    const int head = vbid & 31, chunk = vbid >> 5;   // XCD-local: head%8 fixed
    const int b = head >> 4, h = head & 15;
    const int w = tid >> 6, lane = tid & 63;
    const int lq = lane & 15, kg = lane >> 4;
    const int r0w = chunk * 64 + w * 16;

    const size_t bh = (size_t)(b * HH + h);
    const size_t bhL = bh * LL;
    const unsigned short* qhb = qhi + (bhL + r0w) * DHD;
    const unsigned short* qlb = qlo + (bhL + r0w) * DHD;
    const unsigned short* khb = khi + bhL * DHD;
    const unsigned short* klb = klo + bhL * DHD;
    const unsigned short* vtb = vt + bh * DHD * LL;

    int lo = r0w - WIN; if (lo < 0) lo = 0;
    int hi = r0w + 15 + WIN; if (hi > LL - 1) hi = LL - 1;
    const bool has0 = (lo > 0);

    // zero P pad cols [272,296)
    for (int idx = lane; idx < 96; idx += 64) {
        const int rr = idx / 6, cc = 272 + (idx % 6) * 4;
        *(unsigned long long*)&Pl[w][rr][cc] = 0ull;
    }

    half8v qfh[2], qfl[2];
#pragma unroll
    for (int kf = 0; kf < 2; kf++) {
        const int off = lq * DHD + kf * 32 + kg * 8;
        qfh[kf] = *(const half8v*)(qhb + off);
        qfl[kf] = *(const half8v*)(qlb + off);
    }

    // ---- QK^T: 17 frags x 2 kfrags x 3 split terms ----
    f32x4 acc[17];
#pragma unroll
    for (int f = 0; f < 17; f++) {
        int c = lo + f * 16 + lq;
        const int cc = (c > LL - 1) ? (LL - 1) : c;
        const size_t kb = (size_t)cc * DHD;
        const half8v b0h = *(const half8v*)(khb + kb + kg * 8);
        const half8v b0l = *(const half8v*)(klb + kb + kg * 8);
        const half8v b1h = *(const half8v*)(khb + kb + 32 + kg * 8);
        const half8v b1l = *(const half8v*)(klb + kb + 32 + kg * 8);
        f32x4 a = (f32x4){0.f, 0.f, 0.f, 0.f};
        a = __builtin_amdgcn_mfma_f32_16x16x32_f16(qfl[0], b0h, a, 0, 0, 0);
        a = __builtin_amdgcn_mfma_f32_16x16x32_f16(qfh[0], b0l, a, 0, 0, 0);
        a = __builtin_amdgcn_mfma_f32_16x16x32_f16(qfh[0], b0h, a, 0, 0, 0);
        a = __builtin_amdgcn_mfma_f32_16x16x32_f16(qfl[1], b1h, a, 0, 0, 0);
        a = __builtin_amdgcn_mfma_f32_16x16x32_f16(qfh[1], b1l, a, 0, 0, 0);
        a = __builtin_amdgcn_mfma_f32_16x16x32_f16(qfh[1], b1h, a, 0, 0, 0);
        acc[f] = a;
    }

    // ---- col-0 scalar dot ----
    float sc0 = -FLT_MAX;
    if (has0) {
        float part = 0.f;
        const int rowoff = lq * DHD;
#pragma unroll
        for (int e = 0; e < 16; e++) {
            const int d = kg * 16 + e;
            const float qv = h2f_u(qhb[rowoff + d]) + h2f_u(qlb[rowoff + d]);
            const float kv = h2f_u(khb[d]) + h2f_u(klb[d]);
            part = fmaf(qv, kv, part);
        }
        part += __shfl_xor(part, 16);
        part += __shfl_xor(part, 32);
        const float s = part * 0.125f;
        sc0 = (s > 0.f) ? s + pb0[r0w + lq] : -FLT_MAX;
    }
    if (lane < 16) s0s[w][lq] = sc0;

    // ---- gate + bias (C-layout: col = lane&15, row = kg*4+rg) ----
#pragma unroll
    for (int f = 0; f < 17; f++) {
        const int c = lo + f * 16 + lq;
        const bool cok = (c <= hi);
        f32x4 s4 = acc[f];
#pragma unroll
        for (int rg = 0; rg < 4; rg++) {
            const int r = r0w + kg * 4 + rg;
            const bool allowed = cok &&
                ((c == 0) || ((c >= r - WIN) && (c <= r + WIN)));
            const float s = s4[rg] * 0.125f;
            float sc = -FLT_MAX;
            if (allowed && s > 0.f)
                sc = s + pbp[(size_t)r * 272 + f * 16 + lq];
            s4[rg] = sc;
        }
        acc[f] = s4;
    }

    // ---- softmax (in-register, 16-lane butterflies) ----
    float s0r[4], mx[4];
#pragma unroll
    for (int rg = 0; rg < 4; rg++) {
        s0r[rg] = s0s[w][kg * 4 + rg];
        float m = s0r[rg];
#pragma unroll
        for (int f = 0; f < 17; f++) m = fmaxf(m, acc[f][rg]);
        m = fmaxf(m, __shfl_xor(m, 1));
        m = fmaxf(m, __shfl_xor(m, 2));
        m = fmaxf(m, __shfl_xor(m, 4));
        m = fmaxf(m, __shfl_xor(m, 8));
        mx[rg] = m;
    }

    float sum0 = 0.f, sum1 = 0.f, sum2 = 0.f, sum3 = 0.f;
#pragma unroll
    for (int f = 0; f < 17; f++) {
        const float p0_ = __expf(acc[f][0] - mx[0]); sum0 += p0_;
        const float p1_ = __expf(acc[f][1] - mx[1]); sum1 += p1_;
        const float p2_ = __expf(acc[f][2] - mx[2]); sum2 += p2_;
        const float p3_ = __expf(acc[f][3] - mx[3]); sum3 += p3_;
        Pl[w][kg * 4 + 0][f * 16 + lq] = f2h(p0_);
        Pl[w][kg * 4 + 1][f * 16 + lq] = f2h(p1_);
        Pl[w][kg * 4 + 2][f * 16 + lq] = f2h(p2_);
        Pl[w][kg * 4 + 3][f * 16 + lq] = f2h(p3_);
    }

    float inv[4], p0v[4];
    float sums[4] = {sum0, sum1, sum2, sum3};
#pragma unroll
    for (int rg = 0; rg < 4; rg++) {
        float s = sums[rg];
        s += __shfl_xor(s, 1);
        s += __shfl_xor(s, 2);
        s += __shfl_xor(s, 4);
        s += __shfl_xor(s, 8);
        const float p0 = has0 ? __expf(s0r[rg] - mx[rg]) : 0.f;
        p0v[rg] = p0;
        inv[rg] = 1.0f / (s + p0);
    }

    // ---- PV: A = P (LDS fp16), B = V^T (global fp16) ----
    f32x4 pacc[4];
#pragma unroll
    for (int nf = 0; nf < 4; nf++) pacc[nf] = (f32x4){0.f, 0.f, 0.f, 0.f};
#pragma unroll
    for (int kf = 0; kf < 9; kf++) {
        const half8v pa = *(const half8v*)&Pl[w][lq][kf * 32 + kg * 8];
        int c0 = lo + kf * 32 + kg * 8;
        if (c0 > LL - 8) c0 = LL - 8;       // clamped spans have P==0
#pragma unroll
        for (int nf = 0; nf < 4; nf++) {
            const half8v vb =
                *(const half8v*)(vtb + (size_t)(nf * 16 + lq) * LL + c0);
            pacc[nf] = __builtin_amdgcn_mfma_f32_16x16x32_f16(
                pa, vb, pacc[nf], 0, 0, 0);
        }
    }

    // ---- epilogue ----
#pragma unroll
    for (int nf = 0; nf < 4; nf++) {
        const int n = nf * 16 + lq;
        const float v0 = has0 ? h2f_u(vtb[(size_t)n * LL]) : 0.f;
#pragma unroll
        for (int rg = 0; rg < 4; rg++) {
            const int r = r0w + kg * 4 + rg;
            const float o = (pacc[nf][rg] + p0v[rg] * v0) * inv[rg];
            if (r != 0)
                attn16[((size_t)(b * LL + r)) * EE + h * DHD + n] = f2h(o);
        }
    }
}

// ---------------- out-proj: fp16 x fp16 MFMA, f32 out ----------------------
__global__ __launch_bounds__(256) void gemm_o(
    const unsigned short* __restrict__ attn16, const float* __restrict__ Wo,
    const float* __restrict__ bo, float* __restrict__ out)
{
    __shared__ unsigned short Ah[128 * 40], Bh[128 * 40];

    const int tid = threadIdx.x;
    const int w = tid >> 6, lane = tid & 63;
    const int wr = w >> 1, wc = w & 1;
    const int lr16 = lane & 15, kg = lane >> 4;
    const int row0 = blockIdx.y * 128, col0 = blockIdx.x * 128;
    const int srow = tid >> 1, shalf = tid & 1;
    const int sbase = srow * 40 + shalf * 16;

    const unsigned short* arow = attn16 + (size_t)(row0 + srow) * EE + shalf * 16;
    const float* brow = Wo + (size_t)(col0 + srow) * EE + shalf * 16;

    f32x4 acc[4][4];
#pragma unroll
    for (int i = 0; i < 4; i++)
#pragma unroll
        for (int j = 0; j < 4; j++) acc[i][j] = (f32x4){0.f, 0.f, 0.f, 0.f};

    for (int t = 0; t < EE / 32; t++) {
        const int k0 = t * 32;
        const short8v ra0 = *(const short8v*)(arow + k0);
        const short8v ra1 = *(const short8v*)(arow + k0 + 8);
        const float4 f0 = *(const float4*)(brow + k0);
        const float4 f1 = *(const float4*)(brow + k0 + 4);
        const float4 f2 = *(const float4*)(brow + k0 + 8);
        const float4 f3 = *(const float4*)(brow + k0 + 12);
        unsigned short ub[16];
        ub[0] = f2h(f0.x); ub[1] = f2h(f0.y); ub[2] = f2h(f0.z); ub[3] = f2h(f0.w);
        ub[4] = f2h(f1.x); ub[5] = f2h(f1.y); ub[6] = f2h(f1.z); ub[7] = f2h(f1.w);
        ub[8] = f2h(f2.x); ub[9] = f2h(f2.y); ub[10] = f2h(f2.z); ub[11] = f2h(f2.w);
        ub[12] = f2h(f3.x); ub[13] = f2h(f3.y); ub[14] = f2h(f3.z); ub[15] = f2h(f3.w);
        __syncthreads();
        *(short8v*)&Ah[sbase + 0] = ra0;
        *(short8v*)&Ah[sbase + 8] = ra1;
        *(short8v*)&Bh[sbase + 0] = *(short8v*)&ub[0];
        *(short8v*)&Bh[sbase + 8] = *(short8v*)&ub[8];
        __syncthreads();

        half8v af[4], bf[4];
#pragma unroll
        for (int mr = 0; mr < 4; mr++)
            af[mr] = *(const half8v*)&Ah[(wr*64 + mr*16 + lr16)*40 + kg*8];
#pragma unroll
        for (int nr = 0; nr < 4; nr++)
            bf[nr] = *(const half8v*)&Bh[(wc*64 + nr*16 + lr16)*40 + kg*8];
#pragma unroll
        for (int mr = 0; mr < 4; mr++)
#pragma unroll
            for (int nr = 0; nr < 4; nr++)
                acc[mr][nr] = __builtin_amdgcn_mfma_f32_16x16x32_f16(
                    af[mr], bf[nr], acc[mr][nr], 0, 0, 0);
    }

#pragma unroll
    for (int mr = 0; mr < 4; mr++) {
#pragma unroll
        for (int nr = 0; nr < 4; nr++) {
            const int n = col0 + wc * 64 + nr * 16 + lr16;
            const float bb = bo[n];
#pragma unroll
            for (int j = 0; j < 4; j++) {
                const int m = row0 + wr * 64 + mr * 16 + kg * 4 + j;
                out[(size_t)m * EE + n] = acc[mr][nr][j] + bb;
            }
        }
    }
}

extern "C" void kernel_launch(void* const* d_in, const int* in_sizes, int n_in,
                              void* d_out, int out_size, void* d_ws, size_t ws_size,
                              hipStream_t stream) {
    const float* x        = (const float*)d_in[0];
    const float* pos_bias = (const float*)d_in[1];
    const float* Wq = (const float*)d_in[2];
    const float* bq = (const float*)d_in[3];
    const float* Wk = (const float*)d_in[4];
    const float* bk = (const float*)d_in[5];
    const float* Wv = (const float*)d_in[6];
    const float* bv = (const float*)d_in[7];
    const float* Wo = (const float*)d_in[8];
    const float* bo = (const float*)d_in[9];
    float* out = (float*)d_out;

    const size_t M1 = (size_t)1024 * 1024;         // 1M u16 units
    unsigned short* u = (unsigned short*)d_ws;
    unsigned short* xh  = u;                        // 4M
    unsigned short* xl  = u + 4 * M1;               // 4M (dead after gemm_qkv)
    unsigned short* wqh = u + 8 * M1;               // 1M each
    unsigned short* wql = u + 9 * M1;
    unsigned short* wkh = u + 10 * M1;
    unsigned short* wkl = u + 11 * M1;
    unsigned short* qhi = u + 12 * M1;              // 4M each
    unsigned short* qlo = u + 16 * M1;
    unsigned short* khi = u + 20 * M1;
    unsigned short* klo = u + 24 * M1;
    unsigned short* vt  = u + 28 * M1;              // 4M -> 32M u16 = 64 MB
    unsigned short* attn16 = xh;                    // reuse (xh dead post-QKV)
    float* pbp = (float*)(u + 4 * M1);              // reuse xl: 2048*272 f32
    float* pb0 = pbp + (size_t)2048 * 272;          // + 2048 f32

    prep_split<<<dim3(2048), 256, 0, stream>>>(x, Wq, Wk, xh, xl,
                                               wqh, wql, wkh, wkl);
    gemm_qkv<<<dim3(24, 32), 256, 0, stream>>>(xh, xl, wqh, wql, wkh, wkl,
                                               Wv, bq, bk, bv,
                                               qhi, qlo, khi, klo, vt);
    pack_bias<<<dim3(2048), 256, 0, stream>>>(pos_bias, pbp, pb0);
    attn_mfma<<<dim3(1056), 256, 0, stream>>>(qhi, qlo, khi, klo, vt,
                                              pos_bias, pbp, pb0, attn16);
    gemm_o<<<dim3(8, 32), 256, 0, stream>>>(attn16, Wo, bo, out);
}

// Round 13
// 270.463 us; speedup vs baseline: 7.4129x; 1.0228x over previous
//
#include <hip/hip_runtime.h>
#include <float.h>

#define BB 2
#define LL 2048
#define EE 1024
#define HH 16
#define DHD 64
#define WIN 128

typedef __attribute__((ext_vector_type(8))) short short8v;       // 8 u16
typedef __attribute__((ext_vector_type(8))) _Float16 half8v;     // 8 fp16
typedef __attribute__((ext_vector_type(4))) float f32x4;

static __device__ __forceinline__ unsigned short f2h(float f) {
    union { _Float16 h; unsigned short u; } x; x.h = (_Float16)f; return x.u;
}
static __device__ __forceinline__ float h2f_u(unsigned short u) {
    union { unsigned short u; _Float16 h; } x{u}; return (float)x.h;
}
static __device__ __forceinline__ void f2h_split(float f, unsigned short& hi,
                                                 unsigned short& lo) {
    _Float16 h = (_Float16)f;          // RNE
    _Float16 l = (_Float16)(f - (float)h);
    union { _Float16 h; unsigned short u; } uh, ul;
    uh.h = h; ul.h = l;
    hi = uh.u; lo = ul.u;
}

// ---------------- prep: split x, Wq, Wk into fp16 hi/lo planes -------------
__global__ __launch_bounds__(256) void prep_split(
    const float* __restrict__ x, const float* __restrict__ Wq,
    const float* __restrict__ Wk,
    unsigned short* __restrict__ xh, unsigned short* __restrict__ xl,
    unsigned short* __restrict__ wqh, unsigned short* __restrict__ wql,
    unsigned short* __restrict__ wkh, unsigned short* __restrict__ wkl)
{
    const size_t NX = (size_t)BB * LL * EE;        // 4M
    const size_t NW = (size_t)EE * EE;             // 1M
    const size_t total = NX + 2 * NW;
    const size_t stride = (size_t)gridDim.x * 256 * 4;
    for (size_t i = (size_t)(blockIdx.x * 256 + threadIdx.x) * 4;
         i < total; i += stride) {
        const float* src; unsigned short *dh, *dl; size_t off;
        if (i < NX)            { src = x;  dh = xh;  dl = xl;  off = i; }
        else if (i < NX + NW)  { src = Wq; dh = wqh; dl = wql; off = i - NX; }
        else                   { src = Wk; dh = wkh; dl = wkl; off = i - NX - NW; }
        const float4 v = *(const float4*)(src + off);
        ushort4 h4, l4;
        f2h_split(v.x, h4.x, l4.x);
        f2h_split(v.y, h4.y, l4.y);
        f2h_split(v.z, h4.z, l4.z);
        f2h_split(v.w, h4.w, l4.w);
        *(ushort4*)(dh + off) = h4;
        *(ushort4*)(dl + off) = l4;
    }
}

// ---------------- pack pos_bias + convert Wo -> fp16 -----------------------
// pbp[r][t] = pos_bias[r][lo_w(r) + t]; pb0[r] = pos_bias[r][0];
// woh = fp16(Wo) (same RNE as before -> gemm_o bit-identical).
__global__ __launch_bounds__(256) void pack_bias(
    const float* __restrict__ pb, float* __restrict__ pbp,
    float* __restrict__ pb0, const float* __restrict__ Wo,
    unsigned short* __restrict__ woh)
{
    const int r = blockIdx.x;
    int lo_w = (r & ~15) - WIN; if (lo_w < 0) lo_w = 0;
    for (int t = threadIdx.x; t < 272; t += 256) {
        const int c = lo_w + t;
        pbp[(size_t)r * 272 + t] = (c < LL) ? pb[(size_t)r * LL + c] : 0.f;
    }
    if (threadIdx.x == 0) pb0[r] = pb[(size_t)r * LL];
    // Wo conversion: 1M elems as 512K float2, grid 2048x256 = 512K threads
    const size_t i = (size_t)blockIdx.x * 256 + threadIdx.x;
    const float2 v = ((const float2*)Wo)[i];
    ushort2 o2; o2.x = f2h(v.x); o2.y = f2h(v.y);
    ((ushort2*)woh)[i] = o2;
}

// ---------------- fused QKV projection GEMM (software-pipelined) -----------
// grid (24, 32): bx>>3 = regime (0=Q split, 1=K split, 2=V fp16-hi).
// K-loop: barrier -> ds_write(t) -> barrier -> issue loads(t+1) -> MFMA(t),
// so global latency hides under the MFMA section (r11 exposed it each iter).
__global__ __launch_bounds__(256) void gemm_qkv(
    const unsigned short* __restrict__ xh, const unsigned short* __restrict__ xl,
    const unsigned short* __restrict__ wqh, const unsigned short* __restrict__ wql,
    const unsigned short* __restrict__ wkh, const unsigned short* __restrict__ wkl,
    const float* __restrict__ Wv,
    const float* __restrict__ bq, const float* __restrict__ bk,
    const float* __restrict__ bv,
    unsigned short* __restrict__ qhi, unsigned short* __restrict__ qlo,
    unsigned short* __restrict__ khi, unsigned short* __restrict__ klo,
    unsigned short* __restrict__ vt)
{
    __shared__ unsigned short Ah[128 * 40], Al[128 * 40];
    __shared__ unsigned short Bh[128 * 40], Bl[128 * 40];

    const int bx = blockIdx.x;
    const int regime = bx >> 3;              // 0=Q 1=K 2=V (block-uniform)
    const int col0 = (bx & 7) * 128;
    const int row0 = blockIdx.y * 128;
    const int tid = threadIdx.x;
    const int w = tid >> 6, lane = tid & 63;
    const int wr = w >> 1, wc = w & 1;
    const int lr16 = lane & 15, kg = lane >> 4;
    const int srow = tid >> 1, shalf = tid & 1;
    const int sbase = srow * 40 + shalf * 16;

    const unsigned short* bhsrc = (regime == 0) ? wqh : wkh;
    const unsigned short* blsrc = (regime == 0) ? wql : wkl;
    const float* bias = (regime == 0) ? bq : (regime == 1) ? bk : bv;

    const unsigned short* arow_h = xh + (size_t)(row0 + srow) * EE + shalf * 16;
    const unsigned short* arow_l = xl + (size_t)(row0 + srow) * EE + shalf * 16;
    const unsigned short* brow_h = bhsrc + (size_t)(col0 + srow) * EE + shalf * 16;
    const unsigned short* brow_l = blsrc + (size_t)(col0 + srow) * EE + shalf * 16;
    const float* vrow = Wv + (size_t)(col0 + srow) * EE + shalf * 16;

    f32x4 acc[4][4];
#pragma unroll
    for (int i = 0; i < 4; i++)
#pragma unroll
        for (int j = 0; j < 4; j++) acc[i][j] = (f32x4){0.f, 0.f, 0.f, 0.f};

    short8v ra0, ra1, la0 = {}, la1 = {}, rb0 = {}, rb1 = {}, lb0 = {}, lb1 = {};
    float4 vf0, vf1, vf2, vf3;

    // prefetch tile 0
    {
        ra0 = *(const short8v*)(arow_h + 0);
        ra1 = *(const short8v*)(arow_h + 8);
        if (regime < 2) {
            la0 = *(const short8v*)(arow_l + 0);
            la1 = *(const short8v*)(arow_l + 8);
            rb0 = *(const short8v*)(brow_h + 0);
            rb1 = *(const short8v*)(brow_h + 8);
            lb0 = *(const short8v*)(brow_l + 0);
            lb1 = *(const short8v*)(brow_l + 8);
        } else {
            vf0 = *(const float4*)(vrow + 0);
            vf1 = *(const float4*)(vrow + 4);
            vf2 = *(const float4*)(vrow + 8);
            vf3 = *(const float4*)(vrow + 12);
        }
    }

    for (int t = 0; t < EE / 32; t++) {
        __syncthreads();                         // prev iter's ds_reads done
        *(short8v*)&Ah[sbase + 0] = ra0;
        *(short8v*)&Ah[sbase + 8] = ra1;
        if (regime < 2) {
            *(short8v*)&Al[sbase + 0] = la0;
            *(short8v*)&Al[sbase + 8] = la1;
            *(short8v*)&Bh[sbase + 0] = rb0;
            *(short8v*)&Bh[sbase + 8] = rb1;
            *(short8v*)&Bl[sbase + 0] = lb0;
            *(short8v*)&Bl[sbase + 8] = lb1;
        } else {
            unsigned short ub[16];
            ub[0] = f2h(vf0.x); ub[1] = f2h(vf0.y); ub[2] = f2h(vf0.z); ub[3] = f2h(vf0.w);
            ub[4] = f2h(vf1.x); ub[5] = f2h(vf1.y); ub[6] = f2h(vf1.z); ub[7] = f2h(vf1.w);
            ub[8] = f2h(vf2.x); ub[9] = f2h(vf2.y); ub[10] = f2h(vf2.z); ub[11] = f2h(vf2.w);
            ub[12] = f2h(vf3.x); ub[13] = f2h(vf3.y); ub[14] = f2h(vf3.z); ub[15] = f2h(vf3.w);
            *(short8v*)&Bh[sbase + 0] = *(short8v*)&ub[0];
            *(short8v*)&Bh[sbase + 8] = *(short8v*)&ub[8];
        }
        __syncthreads();                         // writes visible

        // issue loads for t+1 (no wait -> latency hides under MFMA below)
        if (t + 1 < EE / 32) {
            const int k0 = (t + 1) * 32;
            ra0 = *(const short8v*)(arow_h + k0);
            ra1 = *(const short8v*)(arow_h + k0 + 8);
            if (regime < 2) {
                la0 = *(const short8v*)(arow_l + k0);
                la1 = *(const short8v*)(arow_l + k0 + 8);
                rb0 = *(const short8v*)(brow_h + k0);
                rb1 = *(const short8v*)(brow_h + k0 + 8);
                lb0 = *(const short8v*)(brow_l + k0);
                lb1 = *(const short8v*)(brow_l + k0 + 8);
            } else {
                vf0 = *(const float4*)(vrow + k0);
                vf1 = *(const float4*)(vrow + k0 + 4);
                vf2 = *(const float4*)(vrow + k0 + 8);
                vf3 = *(const float4*)(vrow + k0 + 12);
            }
        }

        half8v afh[4], afl[4], bfh[4], bfl[4];
#pragma unroll
        for (int mr = 0; mr < 4; mr++) {
            const int off = (wr * 64 + mr * 16 + lr16) * 40 + kg * 8;
            afh[mr] = *(const half8v*)&Ah[off];
            if (regime < 2) afl[mr] = *(const half8v*)&Al[off];
        }
#pragma unroll
        for (int nr = 0; nr < 4; nr++) {
            const int off = (wc * 64 + nr * 16 + lr16) * 40 + kg * 8;
            bfh[nr] = *(const half8v*)&Bh[off];
            if (regime < 2) bfl[nr] = *(const half8v*)&Bl[off];
        }
        if (regime < 2) {
#pragma unroll
            for (int mr = 0; mr < 4; mr++)
#pragma unroll
                for (int nr = 0; nr < 4; nr++) {
                    acc[mr][nr] = __builtin_amdgcn_mfma_f32_16x16x32_f16(
                        afl[mr], bfh[nr], acc[mr][nr], 0, 0, 0);
                    acc[mr][nr] = __builtin_amdgcn_mfma_f32_16x16x32_f16(
                        afh[mr], bfl[nr], acc[mr][nr], 0, 0, 0);
                    acc[mr][nr] = __builtin_amdgcn_mfma_f32_16x16x32_f16(
                        afh[mr], bfh[nr], acc[mr][nr], 0, 0, 0);
                }
        } else {
#pragma unroll
            for (int mr = 0; mr < 4; mr++)
#pragma unroll
                for (int nr = 0; nr < 4; nr++)
                    acc[mr][nr] = __builtin_amdgcn_mfma_f32_16x16x32_f16(
                        afh[mr], bfh[nr], acc[mr][nr], 0, 0, 0);
        }
    }

    // epilogue: C/D layout col = lane&15, row = (lane>>4)*4 + reg
#pragma unroll
    for (int mr = 0; mr < 4; mr++) {
#pragma unroll
        for (int nr = 0; nr < 4; nr++) {
            const int n = col0 + wc * 64 + nr * 16 + lr16;
            const float bb = bias[n];
#pragma unroll
            for (int j = 0; j < 4; j++) {
                const int m = row0 + wr * 64 + mr * 16 + kg * 4 + j;
                const float val = acc[mr][nr][j] + bb;
                const int bi = m >> 11, l = m & (LL - 1);
                const int hh = n >> 6, d = n & 63;
                if (regime == 2) {
                    vt[((size_t)(bi * HH + hh) * DHD + d) * LL + l] = f2h(val);
                } else {
                    unsigned short hu, lu;
                    f2h_split(val, hu, lu);
                    const size_t o = ((size_t)(bi * HH + hh) * LL + l) * DHD + d;
                    if (regime == 0) { qhi[o] = hu; qlo[o] = lu; }
                    else             { khi[o] = hu; klo[o] = lu; }
                }
            }
        }
    }
}

// ---------------- MFMA windowed attention + fused row-0 --------------------
// blocks [0,32): dense row-0 path FIRST (overlaps windowed phase).
__global__ __launch_bounds__(256) void attn_mfma(
    const unsigned short* __restrict__ qhi, const unsigned short* __restrict__ qlo,
    const unsigned short* __restrict__ khi, const unsigned short* __restrict__ klo,
    const unsigned short* __restrict__ vt, const float* __restrict__ pos_bias,
    const float* __restrict__ pbp, const float* __restrict__ pb0,
    unsigned short* __restrict__ attn16)
{
    __shared__ __align__(16) unsigned short Pl[4][16][296];
    __shared__ float s0s[4][16];

    const int bid = blockIdx.x;
    const int tid = threadIdx.x;

    if (bid < 32) {
        // ---- dense row 0 for one head (vectorized) ----
        const int head = bid;
        const int b = head >> 4, h = head & 15;
        float* sc = (float*)&Pl[0][0][0];
        float* red = sc + LL;
        float* qs = red + 256;
        const size_t bh = (size_t)(b * HH + h);
        const size_t bhL = bh * LL;

        if (tid < DHD)
            qs[tid] = h2f_u(qhi[bhL * DHD + tid]) + h2f_u(qlo[bhL * DHD + tid]);
        __syncthreads();

        for (int j = tid; j < LL; j += 256) {
            const unsigned short* kh = khi + (bhL + j) * DHD;
            const unsigned short* kl = klo + (bhL + j) * DHD;
            float s = 0.f;
#pragma unroll
            for (int d8 = 0; d8 < 8; d8++) {
                const half8v kh8 = *(const half8v*)(kh + d8 * 8);
                const half8v kl8 = *(const half8v*)(kl + d8 * 8);
#pragma unroll
                for (int e = 0; e < 8; e++)
                    s = fmaf(qs[d8 * 8 + e], (float)kh8[e] + (float)kl8[e], s);
            }
            s *= 0.125f;
            sc[j] = (s > 0.f) ? s + pos_bias[j] : -FLT_MAX;
        }
        __syncthreads();

        float m = -FLT_MAX;
        for (int j = tid; j < LL; j += 256) m = fmaxf(m, sc[j]);
        red[tid] = m;
        __syncthreads();
        for (int s = 128; s > 0; s >>= 1) {
            if (tid < s) red[tid] = fmaxf(red[tid], red[tid + s]);
            __syncthreads();
        }
        m = red[0];
        __syncthreads();

        float lsum = 0.f;
        for (int j = tid; j < LL; j += 256) {
            const float p = expf(sc[j] - m);
            sc[j] = p;
            lsum += p;
        }
        red[tid] = lsum;
        __syncthreads();
        for (int s = 128; s > 0; s >>= 1) {
            if (tid < s) red[tid] += red[tid + s];
            __syncthreads();
        }
        const float inv = 1.0f / red[0];
        __syncthreads();

        const int d = tid & 63, part = tid >> 6;
        float a = 0.f;
        const unsigned short* vcol = vt + (bh * DHD + d) * LL;
        for (int j0 = part * 8; j0 < LL; j0 += 32) {
            const half8v v8 = *(const half8v*)(vcol + j0);
#pragma unroll
            for (int e = 0; e < 8; e++)
                a = fmaf(sc[j0 + e], (float)v8[e], a);
        }
        red[tid] = a;
        __syncthreads();
        if (tid < 64) {
            const float tot = (red[tid] + red[tid + 64]) +
                              (red[tid + 128] + red[tid + 192]);
            attn16[(size_t)b * LL * EE + h * DHD + tid] = f2h(tot * inv);
        }
        return;
    }

    // ---- windowed path ----
    const int vbid = bid - 32;
    const int head = vbid & 31, chunk = vbid >> 5;   // XCD-local: head%8 fixed
    const int b = head >> 4, h = head & 15;
    const int w = tid >> 6, lane = tid & 63;
    const int lq = lane & 15, kg = lane >> 4;
    const int r0w = chunk * 64 + w * 16;

    const size_t bh = (size_t)(b * HH + h);
    const size_t bhL = bh * LL;
    const unsigned short* qhb = qhi + (bhL + r0w) * DHD;
    const unsigned short* qlb = qlo + (bhL + r0w) * DHD;
    const unsigned short* khb = khi + bhL * DHD;
    const unsigned short* klb = klo + bhL * DHD;
    const unsigned short* vtb = vt + bh * DHD * LL;

    int lo = r0w - WIN; if (lo < 0) lo = 0;
    int hi = r0w + 15 + WIN; if (hi > LL - 1) hi = LL - 1;
    const bool has0 = (lo > 0);

    // zero P pad cols [272,296)
    for (int idx = lane; idx < 96; idx += 64) {
        const int rr = idx / 6, cc = 272 + (idx % 6) * 4;
        *(unsigned long long*)&Pl[w][rr][cc] = 0ull;
    }

    half8v qfh[2], qfl[2];
#pragma unroll
    for (int kf = 0; kf < 2; kf++) {
        const int off = lq * DHD + kf * 32 + kg * 8;
        qfh[kf] = *(const half8v*)(qhb + off);
        qfl[kf] = *(const half8v*)(qlb + off);
    }

    // ---- QK^T: 17 frags x 2 kfrags x 3 split terms ----
    f32x4 acc[17];
#pragma unroll
    for (int f = 0; f < 17; f++) {
        int c = lo + f * 16 + lq;
        const int cc = (c > LL - 1) ? (LL - 1) : c;
        const size_t kb = (size_t)cc * DHD;
        const half8v b0h = *(const half8v*)(khb + kb + kg * 8);
        const half8v b0l = *(const half8v*)(klb + kb + kg * 8);
        const half8v b1h = *(const half8v*)(khb + kb + 32 + kg * 8);
        const half8v b1l = *(const half8v*)(klb + kb + 32 + kg * 8);
        f32x4 a = (f32x4){0.f, 0.f, 0.f, 0.f};
        a = __builtin_amdgcn_mfma_f32_16x16x32_f16(qfl[0], b0h, a, 0, 0, 0);
        a = __builtin_amdgcn_mfma_f32_16x16x32_f16(qfh[0], b0l, a, 0, 0, 0);
        a = __builtin_amdgcn_mfma_f32_16x16x32_f16(qfh[0], b0h, a, 0, 0, 0);
        a = __builtin_amdgcn_mfma_f32_16x16x32_f16(qfl[1], b1h, a, 0, 0, 0);
        a = __builtin_amdgcn_mfma_f32_16x16x32_f16(qfh[1], b1l, a, 0, 0, 0);
        a = __builtin_amdgcn_mfma_f32_16x16x32_f16(qfh[1], b1h, a, 0, 0, 0);
        acc[f] = a;
    }

    // ---- col-0 scalar dot ----
    float sc0 = -FLT_MAX;
    if (has0) {
        float part = 0.f;
        const int rowoff = lq * DHD;
#pragma unroll
        for (int e = 0; e < 16; e++) {
            const int d = kg * 16 + e;
            const float qv = h2f_u(qhb[rowoff + d]) + h2f_u(qlb[rowoff + d]);
            const float kv = h2f_u(khb[d]) + h2f_u(klb[d]);
            part = fmaf(qv, kv, part);
        }
        part += __shfl_xor(part, 16);
        part += __shfl_xor(part, 32);
        const float s = part * 0.125f;
        sc0 = (s > 0.f) ? s + pb0[r0w + lq] : -FLT_MAX;
    }
    if (lane < 16) s0s[w][lq] = sc0;

    // ---- gate + bias (C-layout: col = lane&15, row = kg*4+rg) ----
#pragma unroll
    for (int f = 0; f < 17; f++) {
        const int c = lo + f * 16 + lq;
        const bool cok = (c <= hi);
        f32x4 s4 = acc[f];
#pragma unroll
        for (int rg = 0; rg < 4; rg++) {
            const int r = r0w + kg * 4 + rg;
            const bool allowed = cok &&
                ((c == 0) || ((c >= r - WIN) && (c <= r + WIN)));
            const float s = s4[rg] * 0.125f;
            float sc = -FLT_MAX;
            if (allowed && s > 0.f)
                sc = s + pbp[(size_t)r * 272 + f * 16 + lq];
            s4[rg] = sc;
        }
        acc[f] = s4;
    }

    // ---- softmax (in-register, 16-lane butterflies) ----
    float s0r[4], mx[4];
#pragma unroll
    for (int rg = 0; rg < 4; rg++) {
        s0r[rg] = s0s[w][kg * 4 + rg];
        float m = s0r[rg];
#pragma unroll
        for (int f = 0; f < 17; f++) m = fmaxf(m, acc[f][rg]);
        m = fmaxf(m, __shfl_xor(m, 1));
        m = fmaxf(m, __shfl_xor(m, 2));
        m = fmaxf(m, __shfl_xor(m, 4));
        m = fmaxf(m, __shfl_xor(m, 8));
        mx[rg] = m;
    }

    float sum0 = 0.f, sum1 = 0.f, sum2 = 0.f, sum3 = 0.f;
#pragma unroll
    for (int f = 0; f < 17; f++) {
        const float p0_ = __expf(acc[f][0] - mx[0]); sum0 += p0_;
        const float p1_ = __expf(acc[f][1] - mx[1]); sum1 += p1_;
        const float p2_ = __expf(acc[f][2] - mx[2]); sum2 += p2_;
        const float p3_ = __expf(acc[f][3] - mx[3]); sum3 += p3_;
        Pl[w][kg * 4 + 0][f * 16 + lq] = f2h(p0_);
        Pl[w][kg * 4 + 1][f * 16 + lq] = f2h(p1_);
        Pl[w][kg * 4 + 2][f * 16 + lq] = f2h(p2_);
        Pl[w][kg * 4 + 3][f * 16 + lq] = f2h(p3_);
    }

    float inv[4], p0v[4];
    float sums[4] = {sum0, sum1, sum2, sum3};
#pragma unroll
    for (int rg = 0; rg < 4; rg++) {
        float s = sums[rg];
        s += __shfl_xor(s, 1);
        s += __shfl_xor(s, 2);
        s += __shfl_xor(s, 4);
        s += __shfl_xor(s, 8);
        const float p0 = has0 ? __expf(s0r[rg] - mx[rg]) : 0.f;
        p0v[rg] = p0;
        inv[rg] = 1.0f / (s + p0);
    }

    // ---- PV: A = P (LDS fp16), B = V^T (global fp16) ----
    f32x4 pacc[4];
#pragma unroll
    for (int nf = 0; nf < 4; nf++) pacc[nf] = (f32x4){0.f, 0.f, 0.f, 0.f};
#pragma unroll
    for (int kf = 0; kf < 9; kf++) {
        const half8v pa = *(const half8v*)&Pl[w][lq][kf * 32 + kg * 8];
        int c0 = lo + kf * 32 + kg * 8;
        if (c0 > LL - 8) c0 = LL - 8;       // clamped spans have P==0
#pragma unroll
        for (int nf = 0; nf < 4; nf++) {
            const half8v vb =
                *(const half8v*)(vtb + (size_t)(nf * 16 + lq) * LL + c0);
            pacc[nf] = __builtin_amdgcn_mfma_f32_16x16x32_f16(
                pa, vb, pacc[nf], 0, 0, 0);
        }
    }

    // ---- epilogue ----
#pragma unroll
    for (int nf = 0; nf < 4; nf++) {
        const int n = nf * 16 + lq;
        const float v0 = has0 ? h2f_u(vtb[(size_t)n * LL]) : 0.f;
#pragma unroll
        for (int rg = 0; rg < 4; rg++) {
            const int r = r0w + kg * 4 + rg;
            const float o = (pacc[nf][rg] + p0v[rg] * v0) * inv[rg];
            if (r != 0)
                attn16[((size_t)(b * LL + r)) * EE + h * DHD + n] = f2h(o);
        }
    }
}

// ---------------- out-proj: fp16 x fp16 MFMA, pipelined, f32 out -----------
__global__ __launch_bounds__(256) void gemm_o(
    const unsigned short* __restrict__ attn16, const unsigned short* __restrict__ woh,
    const float* __restrict__ bo, float* __restrict__ out)
{
    __shared__ unsigned short Ah[128 * 40], Bh[128 * 40];

    const int tid = threadIdx.x;
    const int w = tid >> 6, lane = tid & 63;
    const int wr = w >> 1, wc = w & 1;
    const int lr16 = lane & 15, kg = lane >> 4;
    const int row0 = blockIdx.y * 128, col0 = blockIdx.x * 128;
    const int srow = tid >> 1, shalf = tid & 1;
    const int sbase = srow * 40 + shalf * 16;

    const unsigned short* arow = attn16 + (size_t)(row0 + srow) * EE + shalf * 16;
    const unsigned short* brow = woh + (size_t)(col0 + srow) * EE + shalf * 16;

    f32x4 acc[4][4];
#pragma unroll
    for (int i = 0; i < 4; i++)
#pragma unroll
        for (int j = 0; j < 4; j++) acc[i][j] = (f32x4){0.f, 0.f, 0.f, 0.f};

    short8v ra0 = *(const short8v*)(arow + 0);
    short8v ra1 = *(const short8v*)(arow + 8);
    short8v rb0 = *(const short8v*)(brow + 0);
    short8v rb1 = *(const short8v*)(brow + 8);

    for (int t = 0; t < EE / 32; t++) {
        __syncthreads();
        *(short8v*)&Ah[sbase + 0] = ra0;
        *(short8v*)&Ah[sbase + 8] = ra1;
        *(short8v*)&Bh[sbase + 0] = rb0;
        *(short8v*)&Bh[sbase + 8] = rb1;
        __syncthreads();

        if (t + 1 < EE / 32) {
            const int k0 = (t + 1) * 32;
            ra0 = *(const short8v*)(arow + k0);
            ra1 = *(const short8v*)(arow + k0 + 8);
            rb0 = *(const short8v*)(brow + k0);
            rb1 = *(const short8v*)(brow + k0 + 8);
        }

        half8v af[4], bf[4];
#pragma unroll
        for (int mr = 0; mr < 4; mr++)
            af[mr] = *(const half8v*)&Ah[(wr*64 + mr*16 + lr16)*40 + kg*8];
#pragma unroll
        for (int nr = 0; nr < 4; nr++)
            bf[nr] = *(const half8v*)&Bh[(wc*64 + nr*16 + lr16)*40 + kg*8];
#pragma unroll
        for (int mr = 0; mr < 4; mr++)
#pragma unroll
            for (int nr = 0; nr < 4; nr++)
                acc[mr][nr] = __builtin_amdgcn_mfma_f32_16x16x32_f16(
                    af[mr], bf[nr], acc[mr][nr], 0, 0, 0);
    }

#pragma unroll
    for (int mr = 0; mr < 4; mr++) {
#pragma unroll
        for (int nr = 0; nr < 4; nr++) {
            const int n = col0 + wc * 64 + nr * 16 + lr16;
            const float bb = bo[n];
#pragma unroll
            for (int j = 0; j < 4; j++) {
                const int m = row0 + wr * 64 + mr * 16 + kg * 4 + j;
                out[(size_t)m * EE + n] = acc[mr][nr][j] + bb;
            }
        }
    }
}

extern "C" void kernel_launch(void* const* d_in, const int* in_sizes, int n_in,
                              void* d_out, int out_size, void* d_ws, size_t ws_size,
                              hipStream_t stream) {
    const float* x        = (const float*)d_in[0];
    const float* pos_bias = (const float*)d_in[1];
    const float* Wq = (const float*)d_in[2];
    const float* bq = (const float*)d_in[3];
    const float* Wk = (const float*)d_in[4];
    const float* bk = (const float*)d_in[5];
    const float* Wv = (const float*)d_in[6];
    const float* bv = (const float*)d_in[7];
    const float* Wo = (const float*)d_in[8];
    const float* bo = (const float*)d_in[9];
    float* out = (float*)d_out;

    const size_t M1 = (size_t)1024 * 1024;         // 1M u16 units
    unsigned short* u = (unsigned short*)d_ws;
    unsigned short* xh  = u;                        // 4M
    unsigned short* xl  = u + 4 * M1;               // 4M (dead after gemm_qkv)
    unsigned short* wqh = u + 8 * M1;               // 1M each
    unsigned short* wql = u + 9 * M1;
    unsigned short* wkh = u + 10 * M1;
    unsigned short* wkl = u + 11 * M1;
    unsigned short* qhi = u + 12 * M1;              // 4M each
    unsigned short* qlo = u + 16 * M1;
    unsigned short* khi = u + 20 * M1;
    unsigned short* klo = u + 24 * M1;
    unsigned short* vt  = u + 28 * M1;              // 4M -> 32M u16 = 64 MB
    unsigned short* attn16 = xh;                    // reuse (xh dead post-QKV)
    float* pbp = (float*)(u + 4 * M1);              // reuse xl: 2048*272 f32
    float* pb0 = pbp + (size_t)2048 * 272;          // + 2048 f32
    unsigned short* woh = u + 7 * M1;               // xl region tail: 1M u16

    prep_split<<<dim3(2048), 256, 0, stream>>>(x, Wq, Wk, xh, xl,
                                               wqh, wql, wkh, wkl);
    gemm_qkv<<<dim3(24, 32), 256, 0, stream>>>(xh, xl, wqh, wql, wkh, wkl,
                                               Wv, bq, bk, bv,
                                               qhi, qlo, khi, klo, vt);
    pack_bias<<<dim3(2048), 256, 0, stream>>>(pos_bias, pbp, pb0, Wo, woh);
    attn_mfma<<<dim3(1056), 256, 0, stream>>>(qhi, qlo, khi, klo, vt,
                                              pos_bias, pbp, pb0, attn16);
    gemm_o<<<dim3(8, 32), 256, 0, stream>>>(attn16, woh, bo, out);
}